// Round 12
// baseline (1197.539 us; speedup 1.0000x reference)
//
#include <hip/hip_runtime.h>
#include <stdint.h>

#define NPOINT 1024
#define NSAMPLE 32
#define NB 16
#define NN 4096
#define BN_EPS 1e-5
#define NPIX (NB*NPOINT*NSAMPLE)   // 524288 pixels (b,s,k)
#define NBLK 8192                  // fused_pass grid

// f32, no FMA contraction (FPS only — verified index-exact vs reference via out0).
__device__ __forceinline__ float sqdist3(float dx, float dy, float dz) {
  #pragma clang fp contract(off)
  float a = dx*dx; float b = dy*dy; float c = dz*dz;
  return (a + b) + c;
}

// ---------------- FPS: 256 thr x 16 pts, packed f64-key argmax (R9-verified) -----
// key = (f32_bits(dist) << 32) | (NN-1 - j): positive finite double, so
// v_max_f64 ordering == uint64 ordering == (dist desc, j asc). Keys unique ->
// fmax tree/ladder exact regardless of distribution. R8: batch-pipelining fails
// (W holds the chain). R10: coord-carry spills (16 key+xyz live) — 2.6x slower.
// This single-batch single-barrier form is the measured optimum (628 us).
#define FPS_T 256
#define FPS_PTS (NN/FPS_T)   // 16
#define FPS_W (FPS_T/64)     // 4 waves

#define DPP_MAX64V(VAR, CTRL)                                                  \
  {                                                                            \
    long long kl = __double_as_longlong(VAR);                                  \
    int lo = (int)(unsigned int)kl, hi = (int)(kl >> 32);                      \
    int olo = __builtin_amdgcn_update_dpp(lo, lo, (CTRL), 0xf, 0xf, false);    \
    int ohi = __builtin_amdgcn_update_dpp(hi, hi, (CTRL), 0xf, 0xf, false);    \
    double ok = __longlong_as_double(((long long)ohi << 32) |                  \
                                     (unsigned long long)(unsigned int)olo);   \
    VAR = fmax(VAR, ok);                                                       \
  }

__global__ __launch_bounds__(256) void fps_kernel(
    const float* __restrict__ xyz, int* __restrict__ cents_g,
    float* __restrict__ out_xyz) {
  __shared__ __align__(16) float4 pos[NN];            // 64 KB
  __shared__ __align__(16) double keybuf[2][FPS_W];   // per-wave maxima, parity dbuf
  __shared__ int cents_l[NPOINT];                     // 4 KB — no vmcnt at barrier
  const int b = blockIdx.x;
  const int t = threadIdx.x;
  const float* base = xyz + (size_t)b * NN * 3;
  for (int i = t; i < NN; i += FPS_T) {
    pos[i] = make_float4(base[3*i+0], base[3*i+1], base[3*i+2], 0.f);
  }
  __syncthreads();
  float px[FPS_PTS], py[FPS_PTS], pz[FPS_PTS], dist[FPS_PTS];
  int lowj[FPS_PTS];
  #pragma unroll
  for (int i = 0; i < FPS_PTS; i++) {
    float4 p = pos[i*FPS_T + t];
    px[i] = p.x; py[i] = p.y; pz[i] = p.z;
    dist[i] = 1e10f;
    lowj[i] = (NN-1) - (i*FPS_T + t);
  }
  const int lane = t & 63, wid = t >> 6;
  int far = 0;
  for (int it = 0; it < NPOINT; it++) {
    if (t == 0) cents_l[it] = far;              // LDS only (carry BEFORE update)
    float4 c = pos[far];                        // uniform-address b128 broadcast
    float nd[FPS_PTS];
    #pragma unroll
    for (int i = 0; i < FPS_PTS; i++) {         // fully independent — no chain
      float d = sqdist3(px[i]-c.x, py[i]-c.y, pz[i]-c.z);
      nd[i] = fminf(dist[i], d);
      dist[i] = nd[i];
    }
    double kk[FPS_PTS];
    #pragma unroll
    for (int i = 0; i < FPS_PTS; i++) {
      kk[i] = __longlong_as_double(
          ((long long)__float_as_int(nd[i]) << 32) |
          (unsigned long long)(unsigned int)lowj[i]);
    }
    // 4-level max tree (dep depth 4, full ILP)
    double m0 = fmax(fmax(kk[0],  kk[1]),  fmax(kk[2],  kk[3]));
    double m1 = fmax(fmax(kk[4],  kk[5]),  fmax(kk[6],  kk[7]));
    double m2 = fmax(fmax(kk[8],  kk[9]),  fmax(kk[10], kk[11]));
    double m3 = fmax(fmax(kk[12], kk[13]), fmax(kk[14], kk[15]));
    double bk = fmax(fmax(m0, m1), fmax(m2, m3));
    // 6-stage wave ladder: lane 63 holds wave max
    DPP_MAX64V(bk, 0x111);
    DPP_MAX64V(bk, 0x112);
    DPP_MAX64V(bk, 0x114);
    DPP_MAX64V(bk, 0x118);
    DPP_MAX64V(bk, 0x142);
    DPP_MAX64V(bk, 0x143);
    const int p = it & 1;
    if (lane == 63) keybuf[p][wid] = bk;        // 1 key per wave (4 total)
    __syncthreads();
    // stage 2: every wave redundantly reduces the 4 wave-maxima (no idle waves,
    // no second barrier). keybuf reuse is fenced by the next iter's barrier.
    double k = keybuf[p][lane & (FPS_W-1)];     // broadcast reads — conflict-free
    DPP_MAX64V(k, 0x111);
    DPP_MAX64V(k, 0x112);                       // lane 3 = max of keys 0..3
    int lo32 = (int)(unsigned int)__double_as_longlong(k);
    far = (NN-1) - __builtin_amdgcn_readlane(lo32, 3);   // SGPR broadcast
  }
  __syncthreads();
  // outputs: cents + new_xyz straight from LDS (write_newxyz fused here)
  for (int i = t; i < NPOINT; i += FPS_T) {
    int j = cents_l[i];
    cents_g[b*NPOINT + i] = j;
    float4 p = pos[j];
    size_t o = ((size_t)b * NPOINT + i) * 3;
    out_xyz[o+0] = p.x;
    out_xyz[o+1] = p.y;
    out_xyz[o+2] = p.z;
  }
}

// ---------------- ball query: F64 distances (the proven discrete-exact fix) ------
__global__ __launch_bounds__(256) void ballquery_kernel(
    const float* __restrict__ xyz, const int* __restrict__ cents_g,
    int* __restrict__ idx) {
  const int w = blockIdx.x * 4 + (threadIdx.x >> 6);
  const int lane = threadIdx.x & 63;
  const int b = w >> 10;
  const double RR = 0.2 * 0.2;
  const int cj = cents_g[w] & (NN-1);
  const float* cptr = xyz + ((size_t)b * NN + cj) * 3;
  const double cx = (double)cptr[0], cy = (double)cptr[1], cz = (double)cptr[2];
  const double cn = cx*cx + cy*cy + cz*cz;
  const float* base = xyz + (size_t)b * NN * 3;
  int* out = idx + (size_t)w * NSAMPLE;
  int have = 0, firstj = 0;
  for (int j0 = 0; j0 < NN; j0 += 64) {
    int j = j0 + lane;
    double x = (double)base[3*j+0];
    double y = (double)base[3*j+1];
    double z = (double)base[3*j+2];
    double pn = x*x + y*y + z*z;
    double d = -2.0*(cx*x + cy*y + cz*z) + cn + pn;
    bool pass = !(d > RR);
    unsigned long long m = __ballot(pass);
    int cnt = __popcll(m);
    if (have == 0 && cnt > 0) firstj = j0 + (__ffsll((unsigned long long)m) - 1);
    if (pass) {
      int pos = have + __popcll(m & ((1ull << lane) - 1ull));
      if (pos < NSAMPLE) out[pos] = j;
    }
    have += cnt;
    if (have >= NSAMPLE) break;
  }
  for (int k = have + lane; k < NSAMPLE; k += 64) out[k] = firstj;
}

// ---------------- prep: transpose weights ONCE into workspace --------------------
// Eliminates per-block uncoalesced scalar transpose loads in the fused trio
// (17/16/32 scalar loads/thread x ~24K blocks -> 4-8 float4 copies/thread).
// Values and LDS layout are identical -> downstream arithmetic bit-exact.
__global__ __launch_bounds__(256) void prep_weights(
    const float* __restrict__ w1, const float* __restrict__ w2,
    const float* __restrict__ w3, float* __restrict__ wt) {
  const int t = threadIdx.x;
  float* wt1 = wt;                // 4288 floats (67x64, cc-major)
  float* wt2 = wt + 4288;         // 4096 floats (64x64, cc-major)
  float* wt3 = wt + 8384;         // 8192 floats (2 halves, each 64x64 cc-major)
  for (int ii = t; ii < 67*64; ii += 256) {
    int oc = ii & 63, cc = ii >> 6;
    wt1[cc*64 + oc] = w1[oc*67 + cc];
  }
  for (int ii = t; ii < 4096; ii += 256) {
    int oc = ii & 63, cc = ii >> 6;
    wt2[cc*64 + oc] = w2[oc*64 + cc];
  }
  for (int ii = t; ii < 8192; ii += 256) {
    int h = ii >> 12, r = ii & 4095;
    int oc = r & 63, cc = r >> 6;
    wt3[h*4096 + cc*64 + oc] = w3[(h*64 + oc)*64 + cc];
  }
}

// ---------------- fused pass: NO ATOMICS — per-block f64 partials ---------------
// STOREY: mode1 stores pre-bias acc (y1), mode2 stores pre-bias acc2 (y2) —
// bit-exact register values, enabling recompute-free later passes.
// WC: stage pre-transposed weights from workspace via contiguous float4 copies.
template<int MODE, bool STOREY, bool WC>
__global__ __launch_bounds__(256) void fused_pass(
    const float* __restrict__ xyz, const float* __restrict__ points,
    const int* __restrict__ cents_g, const int* __restrict__ idx,
    const float* __restrict__ w1, const float* __restrict__ b1,
    const float* __restrict__ w2, const float* __restrict__ b2,
    const float* __restrict__ w3, const float* __restrict__ b3,
    const double* __restrict__ aff1, const double* __restrict__ aff2,
    double* __restrict__ partial, float* __restrict__ pmax, float* __restrict__ pmin,
    float* __restrict__ ystore, const float* __restrict__ wt1) {
  __shared__ __align__(16) float wbuf[67*64];   // w1, then w2, then w3 halves
  __shared__ float xsm[67*68];    // gather in, then bn1 out, then bn2 out
  __shared__ float bsm[64];       // b1, then b3-half
  __shared__ float bsm2[64];      // b2
  __shared__ float sc1m[64], sh1m[64], sc2m[64], sh2m[64];
  const int t = threadIdx.x;
  const int pb = blockIdx.x * 64;
  const int tr = t & 15, tc = t >> 4;
  double* pout = partial + (size_t)blockIdx.x * 256;

  if constexpr (WC) {
    const float4* src = (const float4*)wt1;
    float4* dst = (float4*)wbuf;
    for (int ii = t; ii < 1072; ii += 256) dst[ii] = src[ii];
  } else {
    for (int ii = t; ii < 67*64; ii += 256) {
      int oc = ii & 63, cc = ii >> 6;
      wbuf[cc*64 + oc] = w1[oc*67 + cc];
    }
  }
  if (t < 64) {
    bsm[t] = b1[t];
    if (MODE >= 2) { sc1m[t] = (float)aff1[t]; sh1m[t] = (float)aff1[128+t]; }
    if (MODE >= 3) { sc2m[t] = (float)aff2[t]; sh2m[t] = (float)aff2[128+t]; }
  }
  {
    const int pxl = t >> 2, q = t & 3;
    const int p = pb + pxl;
    const int bs = p >> 5;
    const int b  = p >> 15;
    const int j  = idx[p] & (NN-1);
    const float4* prow = (const float4*)(points + ((size_t)b * NN + j) * 64);
    #pragma unroll
    for (int u = 0; u < 4; u++) {
      float4 v = prow[q*4 + u];
      int c0 = 3 + q*16 + u*4;
      xsm[(c0+0)*68 + pxl] = v.x;
      xsm[(c0+1)*68 + pxl] = v.y;
      xsm[(c0+2)*68 + pxl] = v.z;
      xsm[(c0+3)*68 + pxl] = v.w;
    }
    if (q == 0) {
      const float* xr = xyz + ((size_t)b * NN + j) * 3;
      const int cj = cents_g[bs] & (NN-1);
      const float* ce = xyz + ((size_t)b * NN + cj) * 3;
      xsm[0*68 + pxl] = xr[0] - ce[0];
      xsm[1*68 + pxl] = xr[1] - ce[1];
      xsm[2*68 + pxl] = xr[2] - ce[2];
    }
  }
  __syncthreads();

  // ---- gemm1 (67 -> 64) f32 ----
  float acc[4][4] = {};
  for (int cc = 0; cc < 67; cc++) {
    float4 xv = *(const float4*)&xsm[cc*68 + 4*tr];
    float4 wv = *(const float4*)&wbuf[cc*64 + 4*tc];
    float xa[4] = {xv.x, xv.y, xv.z, xv.w};
    float wa[4] = {wv.x, wv.y, wv.z, wv.w};
    #pragma unroll
    for (int i = 0; i < 4; i++)
      #pragma unroll
      for (int jj = 0; jj < 4; jj++) acc[i][jj] += xa[i]*wa[jj];
  }
  if constexpr (MODE == 1) {
    if constexpr (STOREY) {
      #pragma unroll
      for (int i = 0; i < 4; i++) {
        float4 o = make_float4(acc[i][0], acc[i][1], acc[i][2], acc[i][3]);
        *(float4*)(ystore + ((size_t)(pb + 4*tr + i))*64 + 4*tc) = o;
      }
    }
    double s1[4] = {0,0,0,0}, s2[4] = {0,0,0,0};
    #pragma unroll
    for (int jj = 0; jj < 4; jj++) {
      float bb = bsm[4*tc+jj];
      #pragma unroll
      for (int i = 0; i < 4; i++) {
        double yd = (double)(acc[i][jj] + bb);
        s1[jj] += yd; s2[jj] += yd*yd;
      }
    }
    #pragma unroll
    for (int off = 8; off > 0; off >>= 1)
      #pragma unroll
      for (int jj = 0; jj < 4; jj++) {
        s1[jj] += __shfl_down(s1[jj], off, 16);
        s2[jj] += __shfl_down(s2[jj], off, 16);
      }
    if (tr == 0)
      #pragma unroll
      for (int jj = 0; jj < 4; jj++) {
        pout[4*tc+jj]       = s1[jj];
        pout[128 + 4*tc+jj] = s2[jj];
      }
    return;
  }

  __syncthreads();
  #pragma unroll
  for (int jj = 0; jj < 4; jj++) {
    int oc = 4*tc + jj;
    float bb = bsm[oc], sc = sc1m[oc], sh = sh1m[oc];
    float r[4];
    #pragma unroll
    for (int i = 0; i < 4; i++) r[i] = fmaxf((acc[i][jj] + bb)*sc + sh, 0.f);
    *(float4*)&xsm[oc*68 + 4*tr] = make_float4(r[0], r[1], r[2], r[3]);
  }
  for (int ii = t; ii < 4096; ii += 256) {
    int oc = ii & 63, cc = ii >> 6;
    wbuf[cc*64 + oc] = w2[oc*64 + cc];
  }
  if (t < 64) bsm2[t] = b2[t];
  __syncthreads();

  // ---- gemm2 (64 -> 64) f32 ----
  float acc2[4][4] = {};
  for (int cc = 0; cc < 64; cc++) {
    float4 xv = *(const float4*)&xsm[cc*68 + 4*tr];
    float4 wv = *(const float4*)&wbuf[cc*64 + 4*tc];
    float xa[4] = {xv.x, xv.y, xv.z, xv.w};
    float wa[4] = {wv.x, wv.y, wv.z, wv.w};
    #pragma unroll
    for (int i = 0; i < 4; i++)
      #pragma unroll
      for (int jj = 0; jj < 4; jj++) acc2[i][jj] += xa[i]*wa[jj];
  }
  if constexpr (MODE == 2) {
    if constexpr (STOREY) {
      #pragma unroll
      for (int i = 0; i < 4; i++) {
        float4 o = make_float4(acc2[i][0], acc2[i][1], acc2[i][2], acc2[i][3]);
        *(float4*)(ystore + ((size_t)(pb + 4*tr + i))*64 + 4*tc) = o;
      }
    }
    double s1[4] = {0,0,0,0}, s2[4] = {0,0,0,0};
    #pragma unroll
    for (int jj = 0; jj < 4; jj++) {
      float bb = bsm2[4*tc+jj];
      #pragma unroll
      for (int i = 0; i < 4; i++) {
        double yd = (double)(acc2[i][jj] + bb);
        s1[jj] += yd; s2[jj] += yd*yd;
      }
    }
    #pragma unroll
    for (int off = 8; off > 0; off >>= 1)
      #pragma unroll
      for (int jj = 0; jj < 4; jj++) {
        s1[jj] += __shfl_down(s1[jj], off, 16);
        s2[jj] += __shfl_down(s2[jj], off, 16);
      }
    if (tr == 0)
      #pragma unroll
      for (int jj = 0; jj < 4; jj++) {
        pout[4*tc+jj]       = s1[jj];
        pout[128 + 4*tc+jj] = s2[jj];
      }
    return;
  }

  if constexpr (MODE == 3) {
    __syncthreads();
    #pragma unroll
    for (int jj = 0; jj < 4; jj++) {
      int oc = 4*tc + jj;
      float bb = bsm2[oc], sc = sc2m[oc], sh = sh2m[oc];
      float r[4];
      #pragma unroll
      for (int i = 0; i < 4; i++) r[i] = fmaxf((acc2[i][jj] + bb)*sc + sh, 0.f);
      *(float4*)&xsm[oc*68 + 4*tr] = make_float4(r[0], r[1], r[2], r[3]);
    }
    for (int h = 0; h < 2; h++) {
      for (int ii = t; ii < 4096; ii += 256) {
        int oc = ii & 63, cc = ii >> 6;
        wbuf[cc*64 + oc] = w3[(h*64 + oc)*64 + cc];
      }
      if (t < 64) bsm[t] = b3[h*64 + t];
      __syncthreads();
      float acc3[4][4] = {};
      for (int cc = 0; cc < 64; cc++) {
        float4 xv = *(const float4*)&xsm[cc*68 + 4*tr];
        float4 wv = *(const float4*)&wbuf[cc*64 + 4*tc];
        float xa[4] = {xv.x, xv.y, xv.z, xv.w};
        float wa[4] = {wv.x, wv.y, wv.z, wv.w};
        #pragma unroll
        for (int i = 0; i < 4; i++)
          #pragma unroll
          for (int jj = 0; jj < 4; jj++) acc3[i][jj] += xa[i]*wa[jj];
      }
      double s1[4] = {0,0,0,0}, s2[4] = {0,0,0,0};
      float pmx[4], pmn[4];
      #pragma unroll
      for (int jj = 0; jj < 4; jj++) { pmx[jj] = -3.4e38f; pmn[jj] = 3.4e38f; }
      #pragma unroll
      for (int jj = 0; jj < 4; jj++) {
        float bb = bsm[4*tc+jj];
        #pragma unroll
        for (int i = 0; i < 4; i++) {
          float y = acc3[i][jj] + bb;
          double yd = (double)y;
          s1[jj] += yd; s2[jj] += yd*yd;
          pmx[jj] = fmaxf(pmx[jj], y); pmn[jj] = fminf(pmn[jj], y);
        }
      }
      #pragma unroll
      for (int off = 8; off > 0; off >>= 1)
        #pragma unroll
        for (int jj = 0; jj < 4; jj++) {
          s1[jj] += __shfl_down(s1[jj], off, 16);
          s2[jj] += __shfl_down(s2[jj], off, 16);
        }
      if (tr == 0)
        #pragma unroll
        for (int jj = 0; jj < 4; jj++) {
          pout[h*64 + 4*tc+jj]       = s1[jj];
          pout[128 + h*64 + 4*tc+jj] = s2[jj];
        }
      #pragma unroll
      for (int off = 4; off > 0; off >>= 1)
        #pragma unroll
        for (int jj = 0; jj < 4; jj++) {
          pmx[jj] = fmaxf(pmx[jj], __shfl_down(pmx[jj], off, 8));
          pmn[jj] = fminf(pmn[jj], __shfl_down(pmn[jj], off, 8));
        }
      if ((tr & 7) == 0) {
        int bs = (pb >> 5) + (tr >> 3);
        size_t ob = (size_t)bs*128 + h*64 + 4*tc;
        #pragma unroll
        for (int jj = 0; jj < 4; jj++) {
          pmax[ob + jj] = pmx[jj];
          pmin[ob + jj] = pmn[jj];
        }
      }
      __syncthreads();
    }
  }
}

// ---------------- fused_mid: load y1 -> bn1+relu -> gemm2 -> stats2, store y2 ----
template<bool WC>
__global__ __launch_bounds__(256) void fused_mid(
    const float* __restrict__ y1, const float* __restrict__ b1,
    const float* __restrict__ w2, const float* __restrict__ b2,
    const double* __restrict__ aff1,
    double* __restrict__ partial, float* __restrict__ y2,
    const float* __restrict__ wt2) {
  __shared__ __align__(16) float wbuf[64*64];
  __shared__ float xsm[64*68];
  __shared__ float bsm[64];      // b1
  __shared__ float bsm2[64];     // b2
  __shared__ float sc1m[64], sh1m[64];
  const int t = threadIdx.x;
  const int pb = blockIdx.x * 64;
  const int tr = t & 15, tc = t >> 4;
  double* pout = partial + (size_t)blockIdx.x * 256;

  if constexpr (WC) {
    const float4* src = (const float4*)wt2;
    float4* dst = (float4*)wbuf;
    for (int ii = t; ii < 1024; ii += 256) dst[ii] = src[ii];
  } else {
    for (int ii = t; ii < 4096; ii += 256) {
      int oc = ii & 63, cc = ii >> 6;
      wbuf[cc*64 + oc] = w2[oc*64 + cc];
    }
  }
  if (t < 64) {
    bsm[t] = b1[t]; bsm2[t] = b2[t];
    sc1m[t] = (float)aff1[t]; sh1m[t] = (float)aff1[128+t];
  }
  __syncthreads();
  {
    const int pxl = t >> 2, q = t & 3;
    const float* yrow = y1 + ((size_t)(pb + pxl))*64;
    #pragma unroll
    for (int u = 0; u < 4; u++) {
      int c0 = 4*q + 16*u;        // 4q mapping: 2-way LDS write aliasing (free)
      float4 v = *(const float4*)(yrow + c0);
      xsm[(c0+0)*68 + pxl] = fmaxf((v.x + bsm[c0+0])*sc1m[c0+0] + sh1m[c0+0], 0.f);
      xsm[(c0+1)*68 + pxl] = fmaxf((v.y + bsm[c0+1])*sc1m[c0+1] + sh1m[c0+1], 0.f);
      xsm[(c0+2)*68 + pxl] = fmaxf((v.z + bsm[c0+2])*sc1m[c0+2] + sh1m[c0+2], 0.f);
      xsm[(c0+3)*68 + pxl] = fmaxf((v.w + bsm[c0+3])*sc1m[c0+3] + sh1m[c0+3], 0.f);
    }
  }
  __syncthreads();

  float acc2[4][4] = {};
  for (int cc = 0; cc < 64; cc++) {
    float4 xv = *(const float4*)&xsm[cc*68 + 4*tr];
    float4 wv = *(const float4*)&wbuf[cc*64 + 4*tc];
    float xa[4] = {xv.x, xv.y, xv.z, xv.w};
    float wa[4] = {wv.x, wv.y, wv.z, wv.w};
    #pragma unroll
    for (int i = 0; i < 4; i++)
      #pragma unroll
      for (int jj = 0; jj < 4; jj++) acc2[i][jj] += xa[i]*wa[jj];
  }
  #pragma unroll
  for (int i = 0; i < 4; i++) {
    float4 o = make_float4(acc2[i][0], acc2[i][1], acc2[i][2], acc2[i][3]);
    *(float4*)(y2 + ((size_t)(pb + 4*tr + i))*64 + 4*tc) = o;
  }
  double s1[4] = {0,0,0,0}, s2[4] = {0,0,0,0};
  #pragma unroll
  for (int jj = 0; jj < 4; jj++) {
    float bb = bsm2[4*tc+jj];
    #pragma unroll
    for (int i = 0; i < 4; i++) {
      double yd = (double)(acc2[i][jj] + bb);
      s1[jj] += yd; s2[jj] += yd*yd;
    }
  }
  #pragma unroll
  for (int off = 8; off > 0; off >>= 1)
    #pragma unroll
    for (int jj = 0; jj < 4; jj++) {
      s1[jj] += __shfl_down(s1[jj], off, 16);
      s2[jj] += __shfl_down(s2[jj], off, 16);
    }
  if (tr == 0)
    #pragma unroll
    for (int jj = 0; jj < 4; jj++) {
      pout[4*tc+jj]       = s1[jj];
      pout[128 + 4*tc+jj] = s2[jj];
    }
}

// ---------------- fused_last: load y2 -> bn2+relu -> gemm3 -> stats3 + minmax ----
template<bool WC>
__global__ __launch_bounds__(256) void fused_last(
    const float* __restrict__ y2, const float* __restrict__ b2,
    const float* __restrict__ w3, const float* __restrict__ b3,
    const double* __restrict__ aff2,
    double* __restrict__ partial, float* __restrict__ pmax, float* __restrict__ pmin,
    const float* __restrict__ wt3) {
  __shared__ __align__(16) float wbuf[64*64];
  __shared__ float xsm[64*68];
  __shared__ float bsm[64];      // b3 half
  __shared__ float bsm2[64];     // b2
  __shared__ float sc2m[64], sh2m[64];
  const int t = threadIdx.x;
  const int pb = blockIdx.x * 64;
  const int tr = t & 15, tc = t >> 4;
  double* pout = partial + (size_t)blockIdx.x * 256;

  if (t < 64) {
    bsm2[t] = b2[t];
    sc2m[t] = (float)aff2[t]; sh2m[t] = (float)aff2[128+t];
  }
  __syncthreads();
  {
    const int pxl = t >> 2, q = t & 3;
    const float* yrow = y2 + ((size_t)(pb + pxl))*64;
    #pragma unroll
    for (int u = 0; u < 4; u++) {
      int c0 = 4*q + 16*u;
      float4 v = *(const float4*)(yrow + c0);
      xsm[(c0+0)*68 + pxl] = fmaxf((v.x + bsm2[c0+0])*sc2m[c0+0] + sh2m[c0+0], 0.f);
      xsm[(c0+1)*68 + pxl] = fmaxf((v.y + bsm2[c0+1])*sc2m[c0+1] + sh2m[c0+1], 0.f);
      xsm[(c0+2)*68 + pxl] = fmaxf((v.z + bsm2[c0+2])*sc2m[c0+2] + sh2m[c0+2], 0.f);
      xsm[(c0+3)*68 + pxl] = fmaxf((v.w + bsm2[c0+3])*sc2m[c0+3] + sh2m[c0+3], 0.f);
    }
  }
  for (int h = 0; h < 2; h++) {
    if constexpr (WC) {
      const float4* src = (const float4*)(wt3 + h*4096);
      float4* dst = (float4*)wbuf;
      for (int ii = t; ii < 1024; ii += 256) dst[ii] = src[ii];
    } else {
      for (int ii = t; ii < 4096; ii += 256) {
        int oc = ii & 63, cc = ii >> 6;
        wbuf[cc*64 + oc] = w3[(h*64 + oc)*64 + cc];
      }
    }
    if (t < 64) bsm[t] = b3[h*64 + t];
    __syncthreads();
    float acc3[4][4] = {};
    for (int cc = 0; cc < 64; cc++) {
      float4 xv = *(const float4*)&xsm[cc*68 + 4*tr];
      float4 wv = *(const float4*)&wbuf[cc*64 + 4*tc];
      float xa[4] = {xv.x, xv.y, xv.z, xv.w};
      float wa[4] = {wv.x, wv.y, wv.z, wv.w};
      #pragma unroll
      for (int i = 0; i < 4; i++)
        #pragma unroll
        for (int jj = 0; jj < 4; jj++) acc3[i][jj] += xa[i]*wa[jj];
    }
    double s1[4] = {0,0,0,0}, s2[4] = {0,0,0,0};
    float pmx[4], pmn[4];
    #pragma unroll
    for (int jj = 0; jj < 4; jj++) { pmx[jj] = -3.4e38f; pmn[jj] = 3.4e38f; }
    #pragma unroll
    for (int jj = 0; jj < 4; jj++) {
      float bb = bsm[4*tc+jj];
      #pragma unroll
      for (int i = 0; i < 4; i++) {
        float y = acc3[i][jj] + bb;
        double yd = (double)y;
        s1[jj] += yd; s2[jj] += yd*yd;
        pmx[jj] = fmaxf(pmx[jj], y); pmn[jj] = fminf(pmn[jj], y);
      }
    }
    #pragma unroll
    for (int off = 8; off > 0; off >>= 1)
      #pragma unroll
      for (int jj = 0; jj < 4; jj++) {
        s1[jj] += __shfl_down(s1[jj], off, 16);
        s2[jj] += __shfl_down(s2[jj], off, 16);
      }
    if (tr == 0)
      #pragma unroll
      for (int jj = 0; jj < 4; jj++) {
        pout[h*64 + 4*tc+jj]       = s1[jj];
        pout[128 + h*64 + 4*tc+jj] = s2[jj];
      }
    #pragma unroll
    for (int off = 4; off > 0; off >>= 1)
      #pragma unroll
      for (int jj = 0; jj < 4; jj++) {
        pmx[jj] = fmaxf(pmx[jj], __shfl_down(pmx[jj], off, 8));
        pmn[jj] = fminf(pmn[jj], __shfl_down(pmn[jj], off, 8));
      }
    if ((tr & 7) == 0) {
      int bs = (pb >> 5) + (tr >> 3);
      size_t ob = (size_t)bs*128 + h*64 + 4*tc;
      #pragma unroll
      for (int jj = 0; jj < 4; jj++) {
        pmax[ob + jj] = pmx[jj];
        pmin[ob + jj] = pmn[jj];
      }
    }
    __syncthreads();
  }
}

// ---------------- reduce stage A: coalesced 8192->128 row reduction --------------
__global__ __launch_bounds__(256) void reduce_stageA(
    const double* __restrict__ partial, double* __restrict__ partial2) {
  const int t = threadIdx.x;
  const int bid = blockIdx.x;     // [0,128): rows [bid*64, bid*64+64)
  const double* p = partial + (size_t)bid * 64 * 256 + t;
  double a0 = 0.0, a1 = 0.0, a2 = 0.0, a3 = 0.0;
  #pragma unroll 4
  for (int i = 0; i < 64; i += 4) {
    a0 += p[(size_t)(i+0)*256];
    a1 += p[(size_t)(i+1)*256];
    a2 += p[(size_t)(i+2)*256];
    a3 += p[(size_t)(i+3)*256];
  }
  partial2[(size_t)bid*256 + t] = (a0 + a1) + (a2 + a3);
}

// ---------------- reduce stage B: finalize over 128 rows + compute affine --------
__global__ __launch_bounds__(256) void reduce_finalize_kernel(
    const double* __restrict__ partial2,
    const float* __restrict__ g, const float* __restrict__ beta,
    double* __restrict__ aff) {
  __shared__ double sa1[4], sa2[4];
  const int c = blockIdx.x;
  const int t = threadIdx.x;
  double a1 = 0.0, a2 = 0.0;
  for (int blk = t; blk < 128; blk += 256) {
    a1 += partial2[(size_t)blk*256 + c];
    a2 += partial2[(size_t)blk*256 + 128 + c];
  }
  #pragma unroll
  for (int off = 32; off > 0; off >>= 1) {
    a1 += __shfl_down(a1, off);
    a2 += __shfl_down(a2, off);
  }
  const int lane = t & 63, wid = t >> 6;
  if (lane == 0) { sa1[wid] = a1; sa2[wid] = a2; }
  __syncthreads();
  if (t == 0) {
    double s1 = sa1[0] + sa1[1] + sa1[2] + sa1[3];
    double s2 = sa2[0] + sa2[1] + sa2[2] + sa2[3];
    const double invN = 1.0 / (double)NPIX;
    double mean = s1 * invN;
    double var  = s2 * invN - mean*mean;
    var = var > 0.0 ? var : 0.0;
    double r  = 1.0 / sqrt(var + BN_EPS);
    double sc = (double)g[c] * r;
    aff[c]       = sc;
    aff[128 + c] = (double)beta[c] - mean*sc;
  }
}

// ---------------- epilogue: bn3+relu on pooled extremum (monotone trick) ---------
__global__ __launch_bounds__(256) void out_kernel(
    const float* __restrict__ pmax, const float* __restrict__ pmin,
    const double* __restrict__ aff3, float* __restrict__ out_np) {
  int i = blockIdx.x * 256 + threadIdx.x;   // [0, 2097152)
  int oc = i & 127;
  double sc = aff3[oc], sh = aff3[128+oc];
  double v = (sc >= 0.0) ? (double)pmax[i] : (double)pmin[i];
  double y = v*sc + sh;
  out_np[i] = (float)(y > 0.0 ? y : 0.0);
}

extern "C" void kernel_launch(void* const* d_in, const int* in_sizes, int n_in,
                              void* d_out, int out_size, void* d_ws, size_t ws_size,
                              hipStream_t stream) {
  const float* xyz    = (const float*)d_in[0];
  const float* points = (const float*)d_in[1];
  const float* w1  = (const float*)d_in[2];
  const float* b1  = (const float*)d_in[3];
  const float* g1  = (const float*)d_in[4];
  const float* be1 = (const float*)d_in[5];
  const float* w2  = (const float*)d_in[6];
  const float* b2  = (const float*)d_in[7];
  const float* g2  = (const float*)d_in[8];
  const float* be2 = (const float*)d_in[9];
  const float* w3  = (const float*)d_in[10];
  const float* b3  = (const float*)d_in[11];
  const float* g3  = (const float*)d_in[12];
  const float* be3 = (const float*)d_in[13];

  char* ws = (char*)d_ws;
  double* aff     = (double*)(ws + 8192);      // 768 f64
  int*    cents   = (int*)  (ws + 16384);      // 16384 i32
  int*    idx     = (int*)  (ws + 81920);      // 524288 i32
  float*  pmax    = (float*)(ws + 2179072);    // 2097152 f32
  float*  pmin    = (float*)(ws + 10567680);   // 2097152 f32
  double* partial = (double*)(ws + 18956288);  // 8192*256 f64 = 16 MB, ends 35733504
  const size_t OFF_Y = 35733504;               // activation cache (gated on ws_size)
  const size_t SZ_Y  = (size_t)NPIX * 64 * 4;  // 134217728
  float* ycache1 = (float*)(ws + OFF_Y);
  float* ycache2 = (float*)(ws + OFF_Y + SZ_Y);
  const size_t WOFF = OFF_Y + 2*SZ_Y;          // 304168960: transposed weights
  const size_t WT_BYTES = (4288 + 4096 + 8192) * 4;   // 66304
  float* wt = (float*)(ws + WOFF);
  const bool full_path = ws_size >= OFF_Y + 2*SZ_Y;   // >= ~304 MB
  const bool mid_path  = ws_size >= OFF_Y + SZ_Y;     // >= ~170 MB
  const bool wcache    = ws_size >= WOFF + WT_BYTES;
  // stage-A scratch (128*256 f64 = 256 KB), borrowed from provably-dead regions:
  //  - p2a = pmax region (pmax written only AFTER reduces 1 & 2 in every path)
  //  - p2b = idx region (idx consumed BEFORE reduce 3 in every path)
  double* p2a = (double*)pmax;
  double* p2b = (double*)idx;
  float* out_xyz = (float*)d_out;                          // f32 new_xyz
  float* out_np  = (float*)d_out + (size_t)NB*NPOINT*3;    // f32 new_points

  fps_kernel        <<<16,   256, 0, stream>>>(xyz, cents, out_xyz);
  ballquery_kernel  <<<4096, 256, 0, stream>>>(xyz, cents, idx);
  if (full_path && wcache) {
    prep_weights      <<<1,   256, 0, stream>>>(w1, w2, w3, wt);
    fused_pass<1,true,true> <<<NBLK, 256, 0, stream>>>(xyz, points, cents, idx,
                                                   w1,b1,w2,b2,w3,b3,
                                                   aff, aff+256, partial, pmax, pmin,
                                                   ycache1, wt);
    reduce_stageA     <<<128, 256, 0, stream>>>(partial, p2a);
    reduce_finalize_kernel<<<64, 256, 0, stream>>>(p2a, g1, be1, aff);
    fused_mid<true>   <<<NBLK, 256, 0, stream>>>(ycache1, b1, w2, b2, aff, partial,
                                                 ycache2, wt + 4288);
    reduce_stageA     <<<128, 256, 0, stream>>>(partial, p2a);
    reduce_finalize_kernel<<<64, 256, 0, stream>>>(p2a, g2, be2, aff+256);
    fused_last<true>  <<<NBLK, 256, 0, stream>>>(ycache2, b2, w3, b3, aff+256,
                                                 partial, pmax, pmin, wt + 8384);
    reduce_stageA     <<<128, 256, 0, stream>>>(partial, p2b);
    reduce_finalize_kernel<<<128, 256, 0, stream>>>(p2b, g3, be3, aff+512);
  } else if (full_path) {
    fused_pass<1,true,false> <<<NBLK, 256, 0, stream>>>(xyz, points, cents, idx,
                                                   w1,b1,w2,b2,w3,b3,
                                                   aff, aff+256, partial, pmax, pmin,
                                                   ycache1, nullptr);
    reduce_stageA     <<<128, 256, 0, stream>>>(partial, p2a);
    reduce_finalize_kernel<<<64, 256, 0, stream>>>(p2a, g1, be1, aff);
    fused_mid<false>  <<<NBLK, 256, 0, stream>>>(ycache1, b1, w2, b2, aff, partial,
                                                 ycache2, nullptr);
    reduce_stageA     <<<128, 256, 0, stream>>>(partial, p2a);
    reduce_finalize_kernel<<<64, 256, 0, stream>>>(p2a, g2, be2, aff+256);
    fused_last<false> <<<NBLK, 256, 0, stream>>>(ycache2, b2, w3, b3, aff+256,
                                                 partial, pmax, pmin, nullptr);
    reduce_stageA     <<<128, 256, 0, stream>>>(partial, p2b);
    reduce_finalize_kernel<<<128, 256, 0, stream>>>(p2b, g3, be3, aff+512);
  } else if (mid_path) {
    fused_pass<1,false,false> <<<NBLK, 256, 0, stream>>>(xyz, points, cents, idx,
                                                   w1,b1,w2,b2,w3,b3,
                                                   aff, aff+256, partial, pmax, pmin,
                                                   nullptr, nullptr);
    reduce_stageA     <<<128, 256, 0, stream>>>(partial, p2a);
    reduce_finalize_kernel<<<64, 256, 0, stream>>>(p2a, g1, be1, aff);
    fused_pass<2,true,false>  <<<NBLK, 256, 0, stream>>>(xyz, points, cents, idx,
                                                   w1,b1,w2,b2,w3,b3,
                                                   aff, aff+256, partial, pmax, pmin,
                                                   ycache1, nullptr);
    reduce_stageA     <<<128, 256, 0, stream>>>(partial, p2a);
    reduce_finalize_kernel<<<64, 256, 0, stream>>>(p2a, g2, be2, aff+256);
    fused_last<false> <<<NBLK, 256, 0, stream>>>(ycache1, b2, w3, b3, aff+256,
                                                 partial, pmax, pmin, nullptr);
    reduce_stageA     <<<128, 256, 0, stream>>>(partial, p2b);
    reduce_finalize_kernel<<<128, 256, 0, stream>>>(p2b, g3, be3, aff+512);
  } else {
    fused_pass<1,false,false> <<<NBLK, 256, 0, stream>>>(xyz, points, cents, idx,
                                                   w1,b1,w2,b2,w3,b3,
                                                   aff, aff+256, partial, pmax, pmin,
                                                   nullptr, nullptr);
    reduce_stageA     <<<128, 256, 0, stream>>>(partial, p2a);
    reduce_finalize_kernel<<<64, 256, 0, stream>>>(p2a, g1, be1, aff);
    fused_pass<2,false,false> <<<NBLK, 256, 0, stream>>>(xyz, points, cents, idx,
                                                   w1,b1,w2,b2,w3,b3,
                                                   aff, aff+256, partial, pmax, pmin,
                                                   nullptr, nullptr);
    reduce_stageA     <<<128, 256, 0, stream>>>(partial, p2a);
    reduce_finalize_kernel<<<64, 256, 0, stream>>>(p2a, g2, be2, aff+256);
    fused_pass<3,false,false> <<<NBLK, 256, 0, stream>>>(xyz, points, cents, idx,
                                                   w1,b1,w2,b2,w3,b3,
                                                   aff, aff+256, partial, pmax, pmin,
                                                   nullptr, nullptr);
    reduce_stageA     <<<128, 256, 0, stream>>>(partial, p2b);
    reduce_finalize_kernel<<<128, 256, 0, stream>>>(p2b, g3, be3, aff+512);
  }
  out_kernel        <<<NBLK, 256, 0, stream>>>(pmax, pmin, aff+512, out_np);
}

// Round 13
// 1168.753 us; speedup vs baseline: 1.0246x; 1.0246x over previous
//
#include <hip/hip_runtime.h>
#include <stdint.h>

#define NPOINT 1024
#define NSAMPLE 32
#define NB 16
#define NN 4096
#define BN_EPS 1e-5
#define NPIX (NB*NPOINT*NSAMPLE)   // 524288 pixels (b,s,k)
#define NBLK 8192                  // legacy fused_pass grid
#define NBLK2 4096                 // 2-tile fused grid

// f32, no FMA contraction (FPS only — verified index-exact vs reference via out0).
__device__ __forceinline__ float sqdist3(float dx, float dy, float dz) {
  #pragma clang fp contract(off)
  float a = dx*dx; float b = dy*dy; float c = dz*dz;
  return (a + b) + c;
}

// ---------------- FPS: 256 thr x 16 pts, keys-as-state f64 argmax ----------------
// key = (f32_bits(dist) << 32) | (NN-1 - j): positive finite double, so
// v_max/min_f64 ordering == uint64 ordering == (dist, j) lexicographic. Since the
// index low-word is fixed per point, pack(min(dist,d), j) == fmin(key, pack(d,j))
// BIT-EXACTLY -> per-point state is kept as the packed key (saves the separate
// fminf+repack). R8: batch-pipelining fails (W holds the chain). R10: coord-carry
// spills. This single-batch single-barrier form is the measured optimum.
#define FPS_T 256
#define FPS_PTS (NN/FPS_T)   // 16
#define FPS_W (FPS_T/64)     // 4 waves

#define DPP_MAX64V(VAR, CTRL)                                                  \
  {                                                                            \
    long long kl = __double_as_longlong(VAR);                                  \
    int lo = (int)(unsigned int)kl, hi = (int)(kl >> 32);                      \
    int olo = __builtin_amdgcn_update_dpp(lo, lo, (CTRL), 0xf, 0xf, false);    \
    int ohi = __builtin_amdgcn_update_dpp(hi, hi, (CTRL), 0xf, 0xf, false);    \
    double ok = __longlong_as_double(((long long)ohi << 32) |                  \
                                     (unsigned long long)(unsigned int)olo);   \
    VAR = fmax(VAR, ok);                                                       \
  }

__global__ __launch_bounds__(256) void fps_kernel(
    const float* __restrict__ xyz, int* __restrict__ cents_g,
    float* __restrict__ out_xyz) {
  __shared__ __align__(16) float4 pos[NN];            // 64 KB
  __shared__ __align__(16) double keybuf[2][FPS_W];   // per-wave maxima, parity dbuf
  __shared__ int cents_l[NPOINT];                     // 4 KB — no vmcnt at barrier
  const int b = blockIdx.x;
  const int t = threadIdx.x;
  const float* base = xyz + (size_t)b * NN * 3;
  for (int i = t; i < NN; i += FPS_T) {
    pos[i] = make_float4(base[3*i+0], base[3*i+1], base[3*i+2], 0.f);
  }
  __syncthreads();
  float px[FPS_PTS], py[FPS_PTS], pz[FPS_PTS];
  double kk[FPS_PTS];
  int lowj[FPS_PTS];
  #pragma unroll
  for (int i = 0; i < FPS_PTS; i++) {
    float4 p = pos[i*FPS_T + t];
    px[i] = p.x; py[i] = p.y; pz[i] = p.z;
    lowj[i] = (NN-1) - (i*FPS_T + t);
    kk[i] = __longlong_as_double(
        ((long long)__float_as_int(1e10f) << 32) |
        (unsigned long long)(unsigned int)lowj[i]);
  }
  const int lane = t & 63, wid = t >> 6;
  int far = 0;
  for (int it = 0; it < NPOINT; it++) {
    if (t == 0) cents_l[it] = far;              // LDS only (carry BEFORE update)
    float4 c = pos[far];                        // uniform-address b128 broadcast
    #pragma unroll
    for (int i = 0; i < FPS_PTS; i++) {         // fully independent — no chain
      float d = sqdist3(px[i]-c.x, py[i]-c.y, pz[i]-c.z);
      double nk = __longlong_as_double(
          ((long long)__float_as_int(d) << 32) |
          (unsigned long long)(unsigned int)lowj[i]);
      kk[i] = fmin(kk[i], nk);                  // == pack(min(dist,d), j) bit-exact
    }
    // 4-level max tree (dep depth 4, full ILP) — reads kk, state preserved
    double m0 = fmax(fmax(kk[0],  kk[1]),  fmax(kk[2],  kk[3]));
    double m1 = fmax(fmax(kk[4],  kk[5]),  fmax(kk[6],  kk[7]));
    double m2 = fmax(fmax(kk[8],  kk[9]),  fmax(kk[10], kk[11]));
    double m3 = fmax(fmax(kk[12], kk[13]), fmax(kk[14], kk[15]));
    double bk = fmax(fmax(m0, m1), fmax(m2, m3));
    // 6-stage wave ladder: lane 63 holds wave max
    DPP_MAX64V(bk, 0x111);
    DPP_MAX64V(bk, 0x112);
    DPP_MAX64V(bk, 0x114);
    DPP_MAX64V(bk, 0x118);
    DPP_MAX64V(bk, 0x142);
    DPP_MAX64V(bk, 0x143);
    const int p = it & 1;
    if (lane == 63) keybuf[p][wid] = bk;        // 1 key per wave (4 total)
    __syncthreads();
    // stage 2: every wave redundantly reduces the 4 wave-maxima (no idle waves,
    // no second barrier). keybuf reuse is fenced by the next iter's barrier.
    double k = keybuf[p][lane & (FPS_W-1)];     // broadcast reads — conflict-free
    DPP_MAX64V(k, 0x111);
    DPP_MAX64V(k, 0x112);                       // lane 3 = max of keys 0..3
    int lo32 = (int)(unsigned int)__double_as_longlong(k);
    far = (NN-1) - __builtin_amdgcn_readlane(lo32, 3);   // SGPR broadcast
  }
  __syncthreads();
  // outputs: cents + new_xyz straight from LDS (write_newxyz fused here)
  for (int i = t; i < NPOINT; i += FPS_T) {
    int j = cents_l[i];
    cents_g[b*NPOINT + i] = j;
    float4 p = pos[j];
    size_t o = ((size_t)b * NPOINT + i) * 3;
    out_xyz[o+0] = p.x;
    out_xyz[o+1] = p.y;
    out_xyz[o+2] = p.z;
  }
}

// ---------------- ball query: F64 distances (the proven discrete-exact fix) ------
__global__ __launch_bounds__(256) void ballquery_kernel(
    const float* __restrict__ xyz, const int* __restrict__ cents_g,
    int* __restrict__ idx) {
  const int w = blockIdx.x * 4 + (threadIdx.x >> 6);
  const int lane = threadIdx.x & 63;
  const int b = w >> 10;
  const double RR = 0.2 * 0.2;
  const int cj = cents_g[w] & (NN-1);
  const float* cptr = xyz + ((size_t)b * NN + cj) * 3;
  const double cx = (double)cptr[0], cy = (double)cptr[1], cz = (double)cptr[2];
  const double cn = cx*cx + cy*cy + cz*cz;
  const float* base = xyz + (size_t)b * NN * 3;
  int* out = idx + (size_t)w * NSAMPLE;
  int have = 0, firstj = 0;
  for (int j0 = 0; j0 < NN; j0 += 64) {
    int j = j0 + lane;
    double x = (double)base[3*j+0];
    double y = (double)base[3*j+1];
    double z = (double)base[3*j+2];
    double pn = x*x + y*y + z*z;
    double d = -2.0*(cx*x + cy*y + cz*z) + cn + pn;
    bool pass = !(d > RR);
    unsigned long long m = __ballot(pass);
    int cnt = __popcll(m);
    if (have == 0 && cnt > 0) firstj = j0 + (__ffsll((unsigned long long)m) - 1);
    if (pass) {
      int pos = have + __popcll(m & ((1ull << lane) - 1ull));
      if (pos < NSAMPLE) out[pos] = j;
    }
    have += cnt;
    if (have >= NSAMPLE) break;
  }
  for (int k = have + lane; k < NSAMPLE; k += 64) out[k] = firstj;
}

// ---------------- fused_first2: 2 tiles/block — gather+gemm1+stats+store y1 ------
// Stages w1 ONCE per block, processes 128 pixels (2x64 tiles), accumulates f64
// stats across tiles in registers. Per-tile arithmetic identical to fused_pass<1>.
__global__ __launch_bounds__(256) void fused_first2(
    const float* __restrict__ xyz, const float* __restrict__ points,
    const int* __restrict__ cents_g, const int* __restrict__ idx,
    const float* __restrict__ w1, const float* __restrict__ b1,
    double* __restrict__ partial, float* __restrict__ ystore) {
  __shared__ float wbuf[67*64];
  __shared__ float xsm[67*68];
  __shared__ float bsm[64];
  const int t = threadIdx.x;
  const int pb0 = blockIdx.x * 128;
  const int tr = t & 15, tc = t >> 4;
  double* pout = partial + (size_t)blockIdx.x * 256;

  for (int ii = t; ii < 67*64; ii += 256) {
    int oc = ii & 63, cc = ii >> 6;
    wbuf[cc*64 + oc] = w1[oc*67 + cc];
  }
  if (t < 64) bsm[t] = b1[t];

  double s1[4] = {0,0,0,0}, s2[4] = {0,0,0,0};
  for (int tile = 0; tile < 2; tile++) {
    const int pb = pb0 + tile*64;
    if (tile) __syncthreads();      // WAR: previous tile's gemm reads complete
    {
      const int pxl = t >> 2, q = t & 3;
      const int p = pb + pxl;
      const int bs = p >> 5;
      const int b  = p >> 15;
      const int j  = idx[p] & (NN-1);
      const float4* prow = (const float4*)(points + ((size_t)b * NN + j) * 64);
      #pragma unroll
      for (int u = 0; u < 4; u++) {
        float4 v = prow[q*4 + u];
        int c0 = 3 + q*16 + u*4;
        xsm[(c0+0)*68 + pxl] = v.x;
        xsm[(c0+1)*68 + pxl] = v.y;
        xsm[(c0+2)*68 + pxl] = v.z;
        xsm[(c0+3)*68 + pxl] = v.w;
      }
      if (q == 0) {
        const float* xr = xyz + ((size_t)b * NN + j) * 3;
        const int cj = cents_g[bs] & (NN-1);
        const float* ce = xyz + ((size_t)b * NN + cj) * 3;
        xsm[0*68 + pxl] = xr[0] - ce[0];
        xsm[1*68 + pxl] = xr[1] - ce[1];
        xsm[2*68 + pxl] = xr[2] - ce[2];
      }
    }
    __syncthreads();                // gather (and tile0: wbuf/bsm) visible

    float acc[4][4] = {};
    for (int cc = 0; cc < 67; cc++) {
      float4 xv = *(const float4*)&xsm[cc*68 + 4*tr];
      float4 wv = *(const float4*)&wbuf[cc*64 + 4*tc];
      float xa[4] = {xv.x, xv.y, xv.z, xv.w};
      float wa[4] = {wv.x, wv.y, wv.z, wv.w};
      #pragma unroll
      for (int i = 0; i < 4; i++)
        #pragma unroll
        for (int jj = 0; jj < 4; jj++) acc[i][jj] += xa[i]*wa[jj];
    }
    #pragma unroll
    for (int i = 0; i < 4; i++) {
      float4 o = make_float4(acc[i][0], acc[i][1], acc[i][2], acc[i][3]);
      *(float4*)(ystore + ((size_t)(pb + 4*tr + i))*64 + 4*tc) = o;
    }
    #pragma unroll
    for (int jj = 0; jj < 4; jj++) {
      float bb = bsm[4*tc+jj];
      #pragma unroll
      for (int i = 0; i < 4; i++) {
        double yd = (double)(acc[i][jj] + bb);
        s1[jj] += yd; s2[jj] += yd*yd;
      }
    }
  }
  #pragma unroll
  for (int off = 8; off > 0; off >>= 1)
    #pragma unroll
    for (int jj = 0; jj < 4; jj++) {
      s1[jj] += __shfl_down(s1[jj], off, 16);
      s2[jj] += __shfl_down(s2[jj], off, 16);
    }
  if (tr == 0)
    #pragma unroll
    for (int jj = 0; jj < 4; jj++) {
      pout[4*tc+jj]       = s1[jj];
      pout[128 + 4*tc+jj] = s2[jj];
    }
}

// ---------------- fused_mid2: 2 tiles/block — y1 -> bn1+relu -> gemm2 -> y2 ------
__global__ __launch_bounds__(256) void fused_mid2(
    const float* __restrict__ y1, const float* __restrict__ b1,
    const float* __restrict__ w2, const float* __restrict__ b2,
    const double* __restrict__ aff1,
    double* __restrict__ partial, float* __restrict__ y2) {
  __shared__ float wbuf[64*64];
  __shared__ float xsm[64*68];
  __shared__ float bsm[64];      // b1
  __shared__ float bsm2[64];     // b2
  __shared__ float sc1m[64], sh1m[64];
  const int t = threadIdx.x;
  const int pb0 = blockIdx.x * 128;
  const int tr = t & 15, tc = t >> 4;
  double* pout = partial + (size_t)blockIdx.x * 256;

  for (int ii = t; ii < 4096; ii += 256) {
    int oc = ii & 63, cc = ii >> 6;
    wbuf[cc*64 + oc] = w2[oc*64 + cc];
  }
  if (t < 64) {
    bsm[t] = b1[t]; bsm2[t] = b2[t];
    sc1m[t] = (float)aff1[t]; sh1m[t] = (float)aff1[128+t];
  }

  double s1[4] = {0,0,0,0}, s2[4] = {0,0,0,0};
  for (int tile = 0; tile < 2; tile++) {
    const int pb = pb0 + tile*64;
    if (tile) __syncthreads();      // WAR vs previous tile's gemm reads
    else __syncthreads();           // bsm/sc/sh staged (needed by bn below)
    {
      const int pxl = t >> 2, q = t & 3;
      const float* yrow = y1 + ((size_t)(pb + pxl))*64;
      #pragma unroll
      for (int u = 0; u < 4; u++) {
        int c0 = 4*q + 16*u;        // 4q mapping: 2-way LDS write aliasing (free)
        float4 v = *(const float4*)(yrow + c0);
        xsm[(c0+0)*68 + pxl] = fmaxf((v.x + bsm[c0+0])*sc1m[c0+0] + sh1m[c0+0], 0.f);
        xsm[(c0+1)*68 + pxl] = fmaxf((v.y + bsm[c0+1])*sc1m[c0+1] + sh1m[c0+1], 0.f);
        xsm[(c0+2)*68 + pxl] = fmaxf((v.z + bsm[c0+2])*sc1m[c0+2] + sh1m[c0+2], 0.f);
        xsm[(c0+3)*68 + pxl] = fmaxf((v.w + bsm[c0+3])*sc1m[c0+3] + sh1m[c0+3], 0.f);
      }
    }
    __syncthreads();

    float acc2[4][4] = {};
    for (int cc = 0; cc < 64; cc++) {
      float4 xv = *(const float4*)&xsm[cc*68 + 4*tr];
      float4 wv = *(const float4*)&wbuf[cc*64 + 4*tc];
      float xa[4] = {xv.x, xv.y, xv.z, xv.w};
      float wa[4] = {wv.x, wv.y, wv.z, wv.w};
      #pragma unroll
      for (int i = 0; i < 4; i++)
        #pragma unroll
        for (int jj = 0; jj < 4; jj++) acc2[i][jj] += xa[i]*wa[jj];
    }
    #pragma unroll
    for (int i = 0; i < 4; i++) {
      float4 o = make_float4(acc2[i][0], acc2[i][1], acc2[i][2], acc2[i][3]);
      *(float4*)(y2 + ((size_t)(pb + 4*tr + i))*64 + 4*tc) = o;
    }
    #pragma unroll
    for (int jj = 0; jj < 4; jj++) {
      float bb = bsm2[4*tc+jj];
      #pragma unroll
      for (int i = 0; i < 4; i++) {
        double yd = (double)(acc2[i][jj] + bb);
        s1[jj] += yd; s2[jj] += yd*yd;
      }
    }
  }
  #pragma unroll
  for (int off = 8; off > 0; off >>= 1)
    #pragma unroll
    for (int jj = 0; jj < 4; jj++) {
      s1[jj] += __shfl_down(s1[jj], off, 16);
      s2[jj] += __shfl_down(s2[jj], off, 16);
    }
  if (tr == 0)
    #pragma unroll
    for (int jj = 0; jj < 4; jj++) {
      pout[4*tc+jj]       = s1[jj];
      pout[128 + 4*tc+jj] = s2[jj];
    }
}

// ---------------- fused_last: load y2 -> bn2+relu -> gemm3 -> stats3 + minmax ----
__global__ __launch_bounds__(256) void fused_last(
    const float* __restrict__ y2, const float* __restrict__ b2,
    const float* __restrict__ w3, const float* __restrict__ b3,
    const double* __restrict__ aff2,
    double* __restrict__ partial, float* __restrict__ pmax, float* __restrict__ pmin) {
  __shared__ float wbuf[64*64];
  __shared__ float xsm[64*68];
  __shared__ float bsm[64];      // b3 half
  __shared__ float bsm2[64];     // b2
  __shared__ float sc2m[64], sh2m[64];
  const int t = threadIdx.x;
  const int pb = blockIdx.x * 64;
  const int tr = t & 15, tc = t >> 4;
  double* pout = partial + (size_t)blockIdx.x * 256;

  if (t < 64) {
    bsm2[t] = b2[t];
    sc2m[t] = (float)aff2[t]; sh2m[t] = (float)aff2[128+t];
  }
  __syncthreads();
  {
    const int pxl = t >> 2, q = t & 3;
    const float* yrow = y2 + ((size_t)(pb + pxl))*64;
    #pragma unroll
    for (int u = 0; u < 4; u++) {
      int c0 = 4*q + 16*u;
      float4 v = *(const float4*)(yrow + c0);
      xsm[(c0+0)*68 + pxl] = fmaxf((v.x + bsm2[c0+0])*sc2m[c0+0] + sh2m[c0+0], 0.f);
      xsm[(c0+1)*68 + pxl] = fmaxf((v.y + bsm2[c0+1])*sc2m[c0+1] + sh2m[c0+1], 0.f);
      xsm[(c0+2)*68 + pxl] = fmaxf((v.z + bsm2[c0+2])*sc2m[c0+2] + sh2m[c0+2], 0.f);
      xsm[(c0+3)*68 + pxl] = fmaxf((v.w + bsm2[c0+3])*sc2m[c0+3] + sh2m[c0+3], 0.f);
    }
  }
  for (int h = 0; h < 2; h++) {
    for (int ii = t; ii < 4096; ii += 256) {
      int oc = ii & 63, cc = ii >> 6;
      wbuf[cc*64 + oc] = w3[(h*64 + oc)*64 + cc];
    }
    if (t < 64) bsm[t] = b3[h*64 + t];
    __syncthreads();
    float acc3[4][4] = {};
    for (int cc = 0; cc < 64; cc++) {
      float4 xv = *(const float4*)&xsm[cc*68 + 4*tr];
      float4 wv = *(const float4*)&wbuf[cc*64 + 4*tc];
      float xa[4] = {xv.x, xv.y, xv.z, xv.w};
      float wa[4] = {wv.x, wv.y, wv.z, wv.w};
      #pragma unroll
      for (int i = 0; i < 4; i++)
        #pragma unroll
        for (int jj = 0; jj < 4; jj++) acc3[i][jj] += xa[i]*wa[jj];
    }
    double s1[4] = {0,0,0,0}, s2[4] = {0,0,0,0};
    float pmx[4], pmn[4];
    #pragma unroll
    for (int jj = 0; jj < 4; jj++) { pmx[jj] = -3.4e38f; pmn[jj] = 3.4e38f; }
    #pragma unroll
    for (int jj = 0; jj < 4; jj++) {
      float bb = bsm[4*tc+jj];
      #pragma unroll
      for (int i = 0; i < 4; i++) {
        float y = acc3[i][jj] + bb;
        double yd = (double)y;
        s1[jj] += yd; s2[jj] += yd*yd;
        pmx[jj] = fmaxf(pmx[jj], y); pmn[jj] = fminf(pmn[jj], y);
      }
    }
    #pragma unroll
    for (int off = 8; off > 0; off >>= 1)
      #pragma unroll
      for (int jj = 0; jj < 4; jj++) {
        s1[jj] += __shfl_down(s1[jj], off, 16);
        s2[jj] += __shfl_down(s2[jj], off, 16);
      }
    if (tr == 0)
      #pragma unroll
      for (int jj = 0; jj < 4; jj++) {
        pout[h*64 + 4*tc+jj]       = s1[jj];
        pout[128 + h*64 + 4*tc+jj] = s2[jj];
      }
    #pragma unroll
    for (int off = 4; off > 0; off >>= 1)
      #pragma unroll
      for (int jj = 0; jj < 4; jj++) {
        pmx[jj] = fmaxf(pmx[jj], __shfl_down(pmx[jj], off, 8));
        pmn[jj] = fminf(pmn[jj], __shfl_down(pmn[jj], off, 8));
      }
    if ((tr & 7) == 0) {
      int bs = (pb >> 5) + (tr >> 3);
      size_t ob = (size_t)bs*128 + h*64 + 4*tc;
      #pragma unroll
      for (int jj = 0; jj < 4; jj++) {
        pmax[ob + jj] = pmx[jj];
        pmin[ob + jj] = pmn[jj];
      }
    }
    __syncthreads();
  }
}

// ---------------- legacy fused_pass (fallback paths only) ------------------------
template<int MODE, bool STOREY>
__global__ __launch_bounds__(256) void fused_pass(
    const float* __restrict__ xyz, const float* __restrict__ points,
    const int* __restrict__ cents_g, const int* __restrict__ idx,
    const float* __restrict__ w1, const float* __restrict__ b1,
    const float* __restrict__ w2, const float* __restrict__ b2,
    const float* __restrict__ w3, const float* __restrict__ b3,
    const double* __restrict__ aff1, const double* __restrict__ aff2,
    double* __restrict__ partial, float* __restrict__ pmax, float* __restrict__ pmin,
    float* __restrict__ ystore) {
  __shared__ float wbuf[67*64];
  __shared__ float xsm[67*68];
  __shared__ float bsm[64];
  __shared__ float bsm2[64];
  __shared__ float sc1m[64], sh1m[64], sc2m[64], sh2m[64];
  const int t = threadIdx.x;
  const int pb = blockIdx.x * 64;
  const int tr = t & 15, tc = t >> 4;
  double* pout = partial + (size_t)blockIdx.x * 256;

  for (int ii = t; ii < 67*64; ii += 256) {
    int oc = ii & 63, cc = ii >> 6;
    wbuf[cc*64 + oc] = w1[oc*67 + cc];
  }
  if (t < 64) {
    bsm[t] = b1[t];
    if (MODE >= 2) { sc1m[t] = (float)aff1[t]; sh1m[t] = (float)aff1[128+t]; }
    if (MODE >= 3) { sc2m[t] = (float)aff2[t]; sh2m[t] = (float)aff2[128+t]; }
  }
  {
    const int pxl = t >> 2, q = t & 3;
    const int p = pb + pxl;
    const int bs = p >> 5;
    const int b  = p >> 15;
    const int j  = idx[p] & (NN-1);
    const float4* prow = (const float4*)(points + ((size_t)b * NN + j) * 64);
    #pragma unroll
    for (int u = 0; u < 4; u++) {
      float4 v = prow[q*4 + u];
      int c0 = 3 + q*16 + u*4;
      xsm[(c0+0)*68 + pxl] = v.x;
      xsm[(c0+1)*68 + pxl] = v.y;
      xsm[(c0+2)*68 + pxl] = v.z;
      xsm[(c0+3)*68 + pxl] = v.w;
    }
    if (q == 0) {
      const float* xr = xyz + ((size_t)b * NN + j) * 3;
      const int cj = cents_g[bs] & (NN-1);
      const float* ce = xyz + ((size_t)b * NN + cj) * 3;
      xsm[0*68 + pxl] = xr[0] - ce[0];
      xsm[1*68 + pxl] = xr[1] - ce[1];
      xsm[2*68 + pxl] = xr[2] - ce[2];
    }
  }
  __syncthreads();

  float acc[4][4] = {};
  for (int cc = 0; cc < 67; cc++) {
    float4 xv = *(const float4*)&xsm[cc*68 + 4*tr];
    float4 wv = *(const float4*)&wbuf[cc*64 + 4*tc];
    float xa[4] = {xv.x, xv.y, xv.z, xv.w};
    float wa[4] = {wv.x, wv.y, wv.z, wv.w};
    #pragma unroll
    for (int i = 0; i < 4; i++)
      #pragma unroll
      for (int jj = 0; jj < 4; jj++) acc[i][jj] += xa[i]*wa[jj];
  }
  if constexpr (MODE == 1) {
    if constexpr (STOREY) {
      #pragma unroll
      for (int i = 0; i < 4; i++) {
        float4 o = make_float4(acc[i][0], acc[i][1], acc[i][2], acc[i][3]);
        *(float4*)(ystore + ((size_t)(pb + 4*tr + i))*64 + 4*tc) = o;
      }
    }
    double s1[4] = {0,0,0,0}, s2[4] = {0,0,0,0};
    #pragma unroll
    for (int jj = 0; jj < 4; jj++) {
      float bb = bsm[4*tc+jj];
      #pragma unroll
      for (int i = 0; i < 4; i++) {
        double yd = (double)(acc[i][jj] + bb);
        s1[jj] += yd; s2[jj] += yd*yd;
      }
    }
    #pragma unroll
    for (int off = 8; off > 0; off >>= 1)
      #pragma unroll
      for (int jj = 0; jj < 4; jj++) {
        s1[jj] += __shfl_down(s1[jj], off, 16);
        s2[jj] += __shfl_down(s2[jj], off, 16);
      }
    if (tr == 0)
      #pragma unroll
      for (int jj = 0; jj < 4; jj++) {
        pout[4*tc+jj]       = s1[jj];
        pout[128 + 4*tc+jj] = s2[jj];
      }
    return;
  }

  __syncthreads();
  #pragma unroll
  for (int jj = 0; jj < 4; jj++) {
    int oc = 4*tc + jj;
    float bb = bsm[oc], sc = sc1m[oc], sh = sh1m[oc];
    float r[4];
    #pragma unroll
    for (int i = 0; i < 4; i++) r[i] = fmaxf((acc[i][jj] + bb)*sc + sh, 0.f);
    *(float4*)&xsm[oc*68 + 4*tr] = make_float4(r[0], r[1], r[2], r[3]);
  }
  for (int ii = t; ii < 4096; ii += 256) {
    int oc = ii & 63, cc = ii >> 6;
    wbuf[cc*64 + oc] = w2[oc*64 + cc];
  }
  if (t < 64) bsm2[t] = b2[t];
  __syncthreads();

  float acc2[4][4] = {};
  for (int cc = 0; cc < 64; cc++) {
    float4 xv = *(const float4*)&xsm[cc*68 + 4*tr];
    float4 wv = *(const float4*)&wbuf[cc*64 + 4*tc];
    float xa[4] = {xv.x, xv.y, xv.z, xv.w};
    float wa[4] = {wv.x, wv.y, wv.z, wv.w};
    #pragma unroll
    for (int i = 0; i < 4; i++)
      #pragma unroll
      for (int jj = 0; jj < 4; jj++) acc2[i][jj] += xa[i]*wa[jj];
  }
  if constexpr (MODE == 2) {
    if constexpr (STOREY) {
      #pragma unroll
      for (int i = 0; i < 4; i++) {
        float4 o = make_float4(acc2[i][0], acc2[i][1], acc2[i][2], acc2[i][3]);
        *(float4*)(ystore + ((size_t)(pb + 4*tr + i))*64 + 4*tc) = o;
      }
    }
    double s1[4] = {0,0,0,0}, s2[4] = {0,0,0,0};
    #pragma unroll
    for (int jj = 0; jj < 4; jj++) {
      float bb = bsm2[4*tc+jj];
      #pragma unroll
      for (int i = 0; i < 4; i++) {
        double yd = (double)(acc2[i][jj] + bb);
        s1[jj] += yd; s2[jj] += yd*yd;
      }
    }
    #pragma unroll
    for (int off = 8; off > 0; off >>= 1)
      #pragma unroll
      for (int jj = 0; jj < 4; jj++) {
        s1[jj] += __shfl_down(s1[jj], off, 16);
        s2[jj] += __shfl_down(s2[jj], off, 16);
      }
    if (tr == 0)
      #pragma unroll
      for (int jj = 0; jj < 4; jj++) {
        pout[4*tc+jj]       = s1[jj];
        pout[128 + 4*tc+jj] = s2[jj];
      }
    return;
  }

  if constexpr (MODE == 3) {
    __syncthreads();
    #pragma unroll
    for (int jj = 0; jj < 4; jj++) {
      int oc = 4*tc + jj;
      float bb = bsm2[oc], sc = sc2m[oc], sh = sh2m[oc];
      float r[4];
      #pragma unroll
      for (int i = 0; i < 4; i++) r[i] = fmaxf((acc2[i][jj] + bb)*sc + sh, 0.f);
      *(float4*)&xsm[oc*68 + 4*tr] = make_float4(r[0], r[1], r[2], r[3]);
    }
    for (int h = 0; h < 2; h++) {
      for (int ii = t; ii < 4096; ii += 256) {
        int oc = ii & 63, cc = ii >> 6;
        wbuf[cc*64 + oc] = w3[(h*64 + oc)*64 + cc];
      }
      if (t < 64) bsm[t] = b3[h*64 + t];
      __syncthreads();
      float acc3[4][4] = {};
      for (int cc = 0; cc < 64; cc++) {
        float4 xv = *(const float4*)&xsm[cc*68 + 4*tr];
        float4 wv = *(const float4*)&wbuf[cc*64 + 4*tc];
        float xa[4] = {xv.x, xv.y, xv.z, xv.w};
        float wa[4] = {wv.x, wv.y, wv.z, wv.w};
        #pragma unroll
        for (int i = 0; i < 4; i++)
          #pragma unroll
          for (int jj = 0; jj < 4; jj++) acc3[i][jj] += xa[i]*wa[jj];
      }
      double s1[4] = {0,0,0,0}, s2[4] = {0,0,0,0};
      float pmx[4], pmn[4];
      #pragma unroll
      for (int jj = 0; jj < 4; jj++) { pmx[jj] = -3.4e38f; pmn[jj] = 3.4e38f; }
      #pragma unroll
      for (int jj = 0; jj < 4; jj++) {
        float bb = bsm[4*tc+jj];
        #pragma unroll
        for (int i = 0; i < 4; i++) {
          float y = acc3[i][jj] + bb;
          double yd = (double)y;
          s1[jj] += yd; s2[jj] += yd*yd;
          pmx[jj] = fmaxf(pmx[jj], y); pmn[jj] = fminf(pmn[jj], y);
        }
      }
      #pragma unroll
      for (int off = 8; off > 0; off >>= 1)
        #pragma unroll
        for (int jj = 0; jj < 4; jj++) {
          s1[jj] += __shfl_down(s1[jj], off, 16);
          s2[jj] += __shfl_down(s2[jj], off, 16);
        }
      if (tr == 0)
        #pragma unroll
        for (int jj = 0; jj < 4; jj++) {
          pout[h*64 + 4*tc+jj]       = s1[jj];
          pout[128 + h*64 + 4*tc+jj] = s2[jj];
        }
      #pragma unroll
      for (int off = 4; off > 0; off >>= 1)
        #pragma unroll
        for (int jj = 0; jj < 4; jj++) {
          pmx[jj] = fmaxf(pmx[jj], __shfl_down(pmx[jj], off, 8));
          pmn[jj] = fminf(pmn[jj], __shfl_down(pmn[jj], off, 8));
        }
      if ((tr & 7) == 0) {
        int bs = (pb >> 5) + (tr >> 3);
        size_t ob = (size_t)bs*128 + h*64 + 4*tc;
        #pragma unroll
        for (int jj = 0; jj < 4; jj++) {
          pmax[ob + jj] = pmx[jj];
          pmin[ob + jj] = pmn[jj];
        }
      }
      __syncthreads();
    }
  }
}

// ---------------- reduce stage A: coalesced row reduction (grid = rows/64) -------
__global__ __launch_bounds__(256) void reduce_stageA(
    const double* __restrict__ partial, double* __restrict__ partial2) {
  const int t = threadIdx.x;
  const int bid = blockIdx.x;     // rows [bid*64, bid*64+64)
  const double* p = partial + (size_t)bid * 64 * 256 + t;
  double a0 = 0.0, a1 = 0.0, a2 = 0.0, a3 = 0.0;
  #pragma unroll 4
  for (int i = 0; i < 64; i += 4) {
    a0 += p[(size_t)(i+0)*256];
    a1 += p[(size_t)(i+1)*256];
    a2 += p[(size_t)(i+2)*256];
    a3 += p[(size_t)(i+3)*256];
  }
  partial2[(size_t)bid*256 + t] = (a0 + a1) + (a2 + a3);
}

// ---------------- reduce stage B: finalize over nb2 rows + compute affine --------
__global__ __launch_bounds__(256) void reduce_finalize_kernel(
    const double* __restrict__ partial2,
    const float* __restrict__ g, const float* __restrict__ beta,
    double* __restrict__ aff, int nb2) {
  __shared__ double sa1[4], sa2[4];
  const int c = blockIdx.x;
  const int t = threadIdx.x;
  double a1 = 0.0, a2 = 0.0;
  for (int blk = t; blk < nb2; blk += 256) {
    a1 += partial2[(size_t)blk*256 + c];
    a2 += partial2[(size_t)blk*256 + 128 + c];
  }
  #pragma unroll
  for (int off = 32; off > 0; off >>= 1) {
    a1 += __shfl_down(a1, off);
    a2 += __shfl_down(a2, off);
  }
  const int lane = t & 63, wid = t >> 6;
  if (lane == 0) { sa1[wid] = a1; sa2[wid] = a2; }
  __syncthreads();
  if (t == 0) {
    double s1 = sa1[0] + sa1[1] + sa1[2] + sa1[3];
    double s2 = sa2[0] + sa2[1] + sa2[2] + sa2[3];
    const double invN = 1.0 / (double)NPIX;
    double mean = s1 * invN;
    double var  = s2 * invN - mean*mean;
    var = var > 0.0 ? var : 0.0;
    double r  = 1.0 / sqrt(var + BN_EPS);
    double sc = (double)g[c] * r;
    aff[c]       = sc;
    aff[128 + c] = (double)beta[c] - mean*sc;
  }
}

// ---------------- epilogue: bn3+relu on pooled extremum (monotone trick) ---------
__global__ __launch_bounds__(256) void out_kernel(
    const float* __restrict__ pmax, const float* __restrict__ pmin,
    const double* __restrict__ aff3, float* __restrict__ out_np) {
  int i = blockIdx.x * 256 + threadIdx.x;   // [0, 2097152)
  int oc = i & 127;
  double sc = aff3[oc], sh = aff3[128+oc];
  double v = (sc >= 0.0) ? (double)pmax[i] : (double)pmin[i];
  double y = v*sc + sh;
  out_np[i] = (float)(y > 0.0 ? y : 0.0);
}

extern "C" void kernel_launch(void* const* d_in, const int* in_sizes, int n_in,
                              void* d_out, int out_size, void* d_ws, size_t ws_size,
                              hipStream_t stream) {
  const float* xyz    = (const float*)d_in[0];
  const float* points = (const float*)d_in[1];
  const float* w1  = (const float*)d_in[2];
  const float* b1  = (const float*)d_in[3];
  const float* g1  = (const float*)d_in[4];
  const float* be1 = (const float*)d_in[5];
  const float* w2  = (const float*)d_in[6];
  const float* b2  = (const float*)d_in[7];
  const float* g2  = (const float*)d_in[8];
  const float* be2 = (const float*)d_in[9];
  const float* w3  = (const float*)d_in[10];
  const float* b3  = (const float*)d_in[11];
  const float* g3  = (const float*)d_in[12];
  const float* be3 = (const float*)d_in[13];

  char* ws = (char*)d_ws;
  double* aff     = (double*)(ws + 8192);      // 768 f64
  int*    cents   = (int*)  (ws + 16384);      // 16384 i32
  int*    idx     = (int*)  (ws + 81920);      // 524288 i32
  float*  pmax    = (float*)(ws + 2179072);    // 2097152 f32
  float*  pmin    = (float*)(ws + 10567680);   // 2097152 f32
  double* partial = (double*)(ws + 18956288);  // 8192*256 f64 = 16 MB, ends 35733504
  const size_t OFF_Y = 35733504;               // activation cache (gated on ws_size)
  const size_t SZ_Y  = (size_t)NPIX * 64 * 4;  // 134217728
  float* ycache1 = (float*)(ws + OFF_Y);
  float* ycache2 = (float*)(ws + OFF_Y + SZ_Y);
  const bool full_path = ws_size >= OFF_Y + 2*SZ_Y;   // >= ~304 MB
  const bool mid_path  = ws_size >= OFF_Y + SZ_Y;     // >= ~170 MB
  // stage-A scratch (<=128*256 f64 = 256 KB), borrowed from provably-dead regions:
  //  - p2a = pmax region (pmax written only AFTER reduces 1 & 2 in every path)
  //  - p2b = idx region (idx consumed BEFORE reduce 3 in every path)
  double* p2a = (double*)pmax;
  double* p2b = (double*)idx;
  float* out_xyz = (float*)d_out;                          // f32 new_xyz
  float* out_np  = (float*)d_out + (size_t)NB*NPOINT*3;    // f32 new_points

  fps_kernel        <<<16,   256, 0, stream>>>(xyz, cents, out_xyz);
  ballquery_kernel  <<<4096, 256, 0, stream>>>(xyz, cents, idx);
  if (full_path) {
    fused_first2      <<<NBLK2, 256, 0, stream>>>(xyz, points, cents, idx, w1, b1,
                                                  partial, ycache1);
    reduce_stageA     <<<64,  256, 0, stream>>>(partial, p2a);
    reduce_finalize_kernel<<<64, 256, 0, stream>>>(p2a, g1, be1, aff, 64);
    fused_mid2        <<<NBLK2, 256, 0, stream>>>(ycache1, b1, w2, b2, aff, partial,
                                                  ycache2);
    reduce_stageA     <<<64,  256, 0, stream>>>(partial, p2a);
    reduce_finalize_kernel<<<64, 256, 0, stream>>>(p2a, g2, be2, aff+256, 64);
    fused_last        <<<NBLK, 256, 0, stream>>>(ycache2, b2, w3, b3, aff+256,
                                                 partial, pmax, pmin);
    reduce_stageA     <<<128, 256, 0, stream>>>(partial, p2b);
    reduce_finalize_kernel<<<128, 256, 0, stream>>>(p2b, g3, be3, aff+512, 128);
  } else if (mid_path) {
    fused_pass<1,false> <<<NBLK, 256, 0, stream>>>(xyz, points, cents, idx,
                                                   w1,b1,w2,b2,w3,b3,
                                                   aff, aff+256, partial, pmax, pmin,
                                                   nullptr);
    reduce_stageA     <<<128, 256, 0, stream>>>(partial, p2a);
    reduce_finalize_kernel<<<64, 256, 0, stream>>>(p2a, g1, be1, aff, 128);
    fused_pass<2,true>  <<<NBLK, 256, 0, stream>>>(xyz, points, cents, idx,
                                                   w1,b1,w2,b2,w3,b3,
                                                   aff, aff+256, partial, pmax, pmin,
                                                   ycache1);
    reduce_stageA     <<<128, 256, 0, stream>>>(partial, p2a);
    reduce_finalize_kernel<<<64, 256, 0, stream>>>(p2a, g2, be2, aff+256, 128);
    fused_last        <<<NBLK, 256, 0, stream>>>(ycache1, b2, w3, b3, aff+256,
                                                 partial, pmax, pmin);
    reduce_stageA     <<<128, 256, 0, stream>>>(partial, p2b);
    reduce_finalize_kernel<<<128, 256, 0, stream>>>(p2b, g3, be3, aff+512, 128);
  } else {
    fused_pass<1,false> <<<NBLK, 256, 0, stream>>>(xyz, points, cents, idx,
                                                   w1,b1,w2,b2,w3,b3,
                                                   aff, aff+256, partial, pmax, pmin,
                                                   nullptr);
    reduce_stageA     <<<128, 256, 0, stream>>>(partial, p2a);
    reduce_finalize_kernel<<<64, 256, 0, stream>>>(p2a, g1, be1, aff, 128);
    fused_pass<2,false> <<<NBLK, 256, 0, stream>>>(xyz, points, cents, idx,
                                                   w1,b1,w2,b2,w3,b3,
                                                   aff, aff+256, partial, pmax, pmin,
                                                   nullptr);
    reduce_stageA     <<<128, 256, 0, stream>>>(partial, p2a);
    reduce_finalize_kernel<<<64, 256, 0, stream>>>(p2a, g2, be2, aff+256, 128);
    fused_pass<3,false> <<<NBLK, 256, 0, stream>>>(xyz, points, cents, idx,
                                                   w1,b1,w2,b2,w3,b3,
                                                   aff, aff+256, partial, pmax, pmin,
                                                   nullptr);
    reduce_stageA     <<<128, 256, 0, stream>>>(partial, p2b);
    reduce_finalize_kernel<<<128, 256, 0, stream>>>(p2b, g3, be3, aff+512, 128);
  }
  out_kernel        <<<NBLK, 256, 0, stream>>>(pmax, pmin, aff+512, out_np);
}

// Round 14
// 1156.772 us; speedup vs baseline: 1.0352x; 1.0104x over previous
//
#include <hip/hip_runtime.h>
#include <stdint.h>

#define NPOINT 1024
#define NSAMPLE 32
#define NB 16
#define NN 4096
#define BN_EPS 1e-5
#define NPIX (NB*NPOINT*NSAMPLE)   // 524288 pixels (b,s,k)
#define NBLK 8192                  // fused_pass grid

// f32, no FMA contraction (FPS only — verified index-exact vs reference via out0).
__device__ __forceinline__ float sqdist3(float dx, float dy, float dz) {
  #pragma clang fp contract(off)
  float a = dx*dx; float b = dy*dy; float c = dz*dz;
  return (a + b) + c;
}

// ---------------- FPS: 256 thr x 16 pts, keys-as-state f64 argmax (R13, 583us) ---
// key = (f32_bits(dist) << 32) | (NN-1 - j): positive finite double, so
// v_max/min_f64 ordering == uint64 ordering == (dist, j) lexicographic. Since the
// index low-word is fixed per point, pack(min(dist,d), j) == fmin(key, pack(d,j))
// BIT-EXACTLY -> per-point state kept as the packed key. R8: batch-pipelining
// fails (W holds the chain). R10: coord-carry spills. This form is the optimum.
#define FPS_T 256
#define FPS_PTS (NN/FPS_T)   // 16
#define FPS_W (FPS_T/64)     // 4 waves

#define DPP_MAX64V(VAR, CTRL)                                                  \
  {                                                                            \
    long long kl = __double_as_longlong(VAR);                                  \
    int lo = (int)(unsigned int)kl, hi = (int)(kl >> 32);                      \
    int olo = __builtin_amdgcn_update_dpp(lo, lo, (CTRL), 0xf, 0xf, false);    \
    int ohi = __builtin_amdgcn_update_dpp(hi, hi, (CTRL), 0xf, 0xf, false);    \
    double ok = __longlong_as_double(((long long)ohi << 32) |                  \
                                     (unsigned long long)(unsigned int)olo);   \
    VAR = fmax(VAR, ok);                                                       \
  }

__global__ __launch_bounds__(256) void fps_kernel(
    const float* __restrict__ xyz, int* __restrict__ cents_g,
    float* __restrict__ out_xyz) {
  __shared__ __align__(16) float4 pos[NN];            // 64 KB
  __shared__ __align__(16) double keybuf[2][FPS_W];   // per-wave maxima, parity dbuf
  __shared__ int cents_l[NPOINT];                     // 4 KB — no vmcnt at barrier
  const int b = blockIdx.x;
  const int t = threadIdx.x;
  const float* base = xyz + (size_t)b * NN * 3;
  for (int i = t; i < NN; i += FPS_T) {
    pos[i] = make_float4(base[3*i+0], base[3*i+1], base[3*i+2], 0.f);
  }
  __syncthreads();
  float px[FPS_PTS], py[FPS_PTS], pz[FPS_PTS];
  double kk[FPS_PTS];
  int lowj[FPS_PTS];
  #pragma unroll
  for (int i = 0; i < FPS_PTS; i++) {
    float4 p = pos[i*FPS_T + t];
    px[i] = p.x; py[i] = p.y; pz[i] = p.z;
    lowj[i] = (NN-1) - (i*FPS_T + t);
    kk[i] = __longlong_as_double(
        ((long long)__float_as_int(1e10f) << 32) |
        (unsigned long long)(unsigned int)lowj[i]);
  }
  const int lane = t & 63, wid = t >> 6;
  int far = 0;
  for (int it = 0; it < NPOINT; it++) {
    if (t == 0) cents_l[it] = far;              // LDS only (carry BEFORE update)
    float4 c = pos[far];                        // uniform-address b128 broadcast
    #pragma unroll
    for (int i = 0; i < FPS_PTS; i++) {         // fully independent — no chain
      float d = sqdist3(px[i]-c.x, py[i]-c.y, pz[i]-c.z);
      double nk = __longlong_as_double(
          ((long long)__float_as_int(d) << 32) |
          (unsigned long long)(unsigned int)lowj[i]);
      kk[i] = fmin(kk[i], nk);                  // == pack(min(dist,d), j) bit-exact
    }
    // 4-level max tree (dep depth 4, full ILP) — reads kk, state preserved
    double m0 = fmax(fmax(kk[0],  kk[1]),  fmax(kk[2],  kk[3]));
    double m1 = fmax(fmax(kk[4],  kk[5]),  fmax(kk[6],  kk[7]));
    double m2 = fmax(fmax(kk[8],  kk[9]),  fmax(kk[10], kk[11]));
    double m3 = fmax(fmax(kk[12], kk[13]), fmax(kk[14], kk[15]));
    double bk = fmax(fmax(m0, m1), fmax(m2, m3));
    // 6-stage wave ladder: lane 63 holds wave max
    DPP_MAX64V(bk, 0x111);
    DPP_MAX64V(bk, 0x112);
    DPP_MAX64V(bk, 0x114);
    DPP_MAX64V(bk, 0x118);
    DPP_MAX64V(bk, 0x142);
    DPP_MAX64V(bk, 0x143);
    const int p = it & 1;
    if (lane == 63) keybuf[p][wid] = bk;        // 1 key per wave (4 total)
    __syncthreads();
    // stage 2: every wave redundantly reduces the 4 wave-maxima (no idle waves,
    // no second barrier). keybuf reuse is fenced by the next iter's barrier.
    double k = keybuf[p][lane & (FPS_W-1)];     // broadcast reads — conflict-free
    DPP_MAX64V(k, 0x111);
    DPP_MAX64V(k, 0x112);                       // lane 3 = max of keys 0..3
    int lo32 = (int)(unsigned int)__double_as_longlong(k);
    far = (NN-1) - __builtin_amdgcn_readlane(lo32, 3);   // SGPR broadcast
  }
  __syncthreads();
  // outputs: cents + new_xyz straight from LDS (write_newxyz fused here)
  for (int i = t; i < NPOINT; i += FPS_T) {
    int j = cents_l[i];
    cents_g[b*NPOINT + i] = j;
    float4 p = pos[j];
    size_t o = ((size_t)b * NPOINT + i) * 3;
    out_xyz[o+0] = p.x;
    out_xyz[o+1] = p.y;
    out_xyz[o+2] = p.z;
  }
}

// ---------------- ball query: F64 distances (the proven discrete-exact fix) ------
__global__ __launch_bounds__(256) void ballquery_kernel(
    const float* __restrict__ xyz, const int* __restrict__ cents_g,
    int* __restrict__ idx) {
  const int w = blockIdx.x * 4 + (threadIdx.x >> 6);
  const int lane = threadIdx.x & 63;
  const int b = w >> 10;
  const double RR = 0.2 * 0.2;
  const int cj = cents_g[w] & (NN-1);
  const float* cptr = xyz + ((size_t)b * NN + cj) * 3;
  const double cx = (double)cptr[0], cy = (double)cptr[1], cz = (double)cptr[2];
  const double cn = cx*cx + cy*cy + cz*cz;
  const float* base = xyz + (size_t)b * NN * 3;
  int* out = idx + (size_t)w * NSAMPLE;
  int have = 0, firstj = 0;
  for (int j0 = 0; j0 < NN; j0 += 64) {
    int j = j0 + lane;
    double x = (double)base[3*j+0];
    double y = (double)base[3*j+1];
    double z = (double)base[3*j+2];
    double pn = x*x + y*y + z*z;
    double d = -2.0*(cx*x + cy*y + cz*z) + cn + pn;
    bool pass = !(d > RR);
    unsigned long long m = __ballot(pass);
    int cnt = __popcll(m);
    if (have == 0 && cnt > 0) firstj = j0 + (__ffsll((unsigned long long)m) - 1);
    if (pass) {
      int pos = have + __popcll(m & ((1ull << lane) - 1ull));
      if (pos < NSAMPLE) out[pos] = j;
    }
    have += cnt;
    if (have >= NSAMPLE) break;
  }
  for (int k = have + lane; k < NSAMPLE; k += 64) out[k] = firstj;
}

// ---------------- fused pass: NO ATOMICS — per-block f64 partials ---------------
// STOREY: mode1 stores pre-bias acc (y1), mode2 stores pre-bias acc2 (y2) —
// bit-exact register values, enabling recompute-free later passes.
// Single-tile (R11-verified): independent 64-pixel blocks overlap gather/gemm
// across the grid better than 2-tile intra-block serialization (R13 lesson).
template<int MODE, bool STOREY>
__global__ __launch_bounds__(256) void fused_pass(
    const float* __restrict__ xyz, const float* __restrict__ points,
    const int* __restrict__ cents_g, const int* __restrict__ idx,
    const float* __restrict__ w1, const float* __restrict__ b1,
    const float* __restrict__ w2, const float* __restrict__ b2,
    const float* __restrict__ w3, const float* __restrict__ b3,
    const double* __restrict__ aff1, const double* __restrict__ aff2,
    double* __restrict__ partial, float* __restrict__ pmax, float* __restrict__ pmin,
    float* __restrict__ ystore) {
  __shared__ float wbuf[67*64];   // w1, then w2, then w3 halves
  __shared__ float xsm[67*68];    // gather in, then bn1 out, then bn2 out
  __shared__ float bsm[64];       // b1, then b3-half
  __shared__ float bsm2[64];      // b2
  __shared__ float sc1m[64], sh1m[64], sc2m[64], sh2m[64];
  const int t = threadIdx.x;
  const int pb = blockIdx.x * 64;
  const int tr = t & 15, tc = t >> 4;
  double* pout = partial + (size_t)blockIdx.x * 256;

  for (int ii = t; ii < 67*64; ii += 256) {
    int oc = ii & 63, cc = ii >> 6;
    wbuf[cc*64 + oc] = w1[oc*67 + cc];
  }
  if (t < 64) {
    bsm[t] = b1[t];
    if (MODE >= 2) { sc1m[t] = (float)aff1[t]; sh1m[t] = (float)aff1[128+t]; }
    if (MODE >= 3) { sc2m[t] = (float)aff2[t]; sh2m[t] = (float)aff2[128+t]; }
  }
  {
    const int pxl = t >> 2, q = t & 3;
    const int p = pb + pxl;
    const int bs = p >> 5;
    const int b  = p >> 15;
    const int j  = idx[p] & (NN-1);
    const float4* prow = (const float4*)(points + ((size_t)b * NN + j) * 64);
    #pragma unroll
    for (int u = 0; u < 4; u++) {
      float4 v = prow[q*4 + u];
      int c0 = 3 + q*16 + u*4;
      xsm[(c0+0)*68 + pxl] = v.x;
      xsm[(c0+1)*68 + pxl] = v.y;
      xsm[(c0+2)*68 + pxl] = v.z;
      xsm[(c0+3)*68 + pxl] = v.w;
    }
    if (q == 0) {
      const float* xr = xyz + ((size_t)b * NN + j) * 3;
      const int cj = cents_g[bs] & (NN-1);
      const float* ce = xyz + ((size_t)b * NN + cj) * 3;
      xsm[0*68 + pxl] = xr[0] - ce[0];
      xsm[1*68 + pxl] = xr[1] - ce[1];
      xsm[2*68 + pxl] = xr[2] - ce[2];
    }
  }
  __syncthreads();

  // ---- gemm1 (67 -> 64) f32 ----
  float acc[4][4] = {};
  for (int cc = 0; cc < 67; cc++) {
    float4 xv = *(const float4*)&xsm[cc*68 + 4*tr];
    float4 wv = *(const float4*)&wbuf[cc*64 + 4*tc];
    float xa[4] = {xv.x, xv.y, xv.z, xv.w};
    float wa[4] = {wv.x, wv.y, wv.z, wv.w};
    #pragma unroll
    for (int i = 0; i < 4; i++)
      #pragma unroll
      for (int jj = 0; jj < 4; jj++) acc[i][jj] += xa[i]*wa[jj];
  }
  if constexpr (MODE == 1) {
    if constexpr (STOREY) {
      #pragma unroll
      for (int i = 0; i < 4; i++) {
        float4 o = make_float4(acc[i][0], acc[i][1], acc[i][2], acc[i][3]);
        *(float4*)(ystore + ((size_t)(pb + 4*tr + i))*64 + 4*tc) = o;
      }
    }
    double s1[4] = {0,0,0,0}, s2[4] = {0,0,0,0};
    #pragma unroll
    for (int jj = 0; jj < 4; jj++) {
      float bb = bsm[4*tc+jj];
      #pragma unroll
      for (int i = 0; i < 4; i++) {
        double yd = (double)(acc[i][jj] + bb);
        s1[jj] += yd; s2[jj] += yd*yd;
      }
    }
    #pragma unroll
    for (int off = 8; off > 0; off >>= 1)
      #pragma unroll
      for (int jj = 0; jj < 4; jj++) {
        s1[jj] += __shfl_down(s1[jj], off, 16);
        s2[jj] += __shfl_down(s2[jj], off, 16);
      }
    if (tr == 0)
      #pragma unroll
      for (int jj = 0; jj < 4; jj++) {
        pout[4*tc+jj]       = s1[jj];
        pout[128 + 4*tc+jj] = s2[jj];
      }
    return;
  }

  __syncthreads();
  #pragma unroll
  for (int jj = 0; jj < 4; jj++) {
    int oc = 4*tc + jj;
    float bb = bsm[oc], sc = sc1m[oc], sh = sh1m[oc];
    float r[4];
    #pragma unroll
    for (int i = 0; i < 4; i++) r[i] = fmaxf((acc[i][jj] + bb)*sc + sh, 0.f);
    *(float4*)&xsm[oc*68 + 4*tr] = make_float4(r[0], r[1], r[2], r[3]);
  }
  for (int ii = t; ii < 4096; ii += 256) {
    int oc = ii & 63, cc = ii >> 6;
    wbuf[cc*64 + oc] = w2[oc*64 + cc];
  }
  if (t < 64) bsm2[t] = b2[t];
  __syncthreads();

  // ---- gemm2 (64 -> 64) f32 ----
  float acc2[4][4] = {};
  for (int cc = 0; cc < 64; cc++) {
    float4 xv = *(const float4*)&xsm[cc*68 + 4*tr];
    float4 wv = *(const float4*)&wbuf[cc*64 + 4*tc];
    float xa[4] = {xv.x, xv.y, xv.z, xv.w};
    float wa[4] = {wv.x, wv.y, wv.z, wv.w};
    #pragma unroll
    for (int i = 0; i < 4; i++)
      #pragma unroll
      for (int jj = 0; jj < 4; jj++) acc2[i][jj] += xa[i]*wa[jj];
  }
  if constexpr (MODE == 2) {
    if constexpr (STOREY) {
      #pragma unroll
      for (int i = 0; i < 4; i++) {
        float4 o = make_float4(acc2[i][0], acc2[i][1], acc2[i][2], acc2[i][3]);
        *(float4*)(ystore + ((size_t)(pb + 4*tr + i))*64 + 4*tc) = o;
      }
    }
    double s1[4] = {0,0,0,0}, s2[4] = {0,0,0,0};
    #pragma unroll
    for (int jj = 0; jj < 4; jj++) {
      float bb = bsm2[4*tc+jj];
      #pragma unroll
      for (int i = 0; i < 4; i++) {
        double yd = (double)(acc2[i][jj] + bb);
        s1[jj] += yd; s2[jj] += yd*yd;
      }
    }
    #pragma unroll
    for (int off = 8; off > 0; off >>= 1)
      #pragma unroll
      for (int jj = 0; jj < 4; jj++) {
        s1[jj] += __shfl_down(s1[jj], off, 16);
        s2[jj] += __shfl_down(s2[jj], off, 16);
      }
    if (tr == 0)
      #pragma unroll
      for (int jj = 0; jj < 4; jj++) {
        pout[4*tc+jj]       = s1[jj];
        pout[128 + 4*tc+jj] = s2[jj];
      }
    return;
  }

  if constexpr (MODE == 3) {
    __syncthreads();
    #pragma unroll
    for (int jj = 0; jj < 4; jj++) {
      int oc = 4*tc + jj;
      float bb = bsm2[oc], sc = sc2m[oc], sh = sh2m[oc];
      float r[4];
      #pragma unroll
      for (int i = 0; i < 4; i++) r[i] = fmaxf((acc2[i][jj] + bb)*sc + sh, 0.f);
      *(float4*)&xsm[oc*68 + 4*tr] = make_float4(r[0], r[1], r[2], r[3]);
    }
    for (int h = 0; h < 2; h++) {
      for (int ii = t; ii < 4096; ii += 256) {
        int oc = ii & 63, cc = ii >> 6;
        wbuf[cc*64 + oc] = w3[(h*64 + oc)*64 + cc];
      }
      if (t < 64) bsm[t] = b3[h*64 + t];
      __syncthreads();
      float acc3[4][4] = {};
      for (int cc = 0; cc < 64; cc++) {
        float4 xv = *(const float4*)&xsm[cc*68 + 4*tr];
        float4 wv = *(const float4*)&wbuf[cc*64 + 4*tc];
        float xa[4] = {xv.x, xv.y, xv.z, xv.w};
        float wa[4] = {wv.x, wv.y, wv.z, wv.w};
        #pragma unroll
        for (int i = 0; i < 4; i++)
          #pragma unroll
          for (int jj = 0; jj < 4; jj++) acc3[i][jj] += xa[i]*wa[jj];
      }
      double s1[4] = {0,0,0,0}, s2[4] = {0,0,0,0};
      float pmx[4], pmn[4];
      #pragma unroll
      for (int jj = 0; jj < 4; jj++) { pmx[jj] = -3.4e38f; pmn[jj] = 3.4e38f; }
      #pragma unroll
      for (int jj = 0; jj < 4; jj++) {
        float bb = bsm[4*tc+jj];
        #pragma unroll
        for (int i = 0; i < 4; i++) {
          float y = acc3[i][jj] + bb;
          double yd = (double)y;
          s1[jj] += yd; s2[jj] += yd*yd;
          pmx[jj] = fmaxf(pmx[jj], y); pmn[jj] = fminf(pmn[jj], y);
        }
      }
      #pragma unroll
      for (int off = 8; off > 0; off >>= 1)
        #pragma unroll
        for (int jj = 0; jj < 4; jj++) {
          s1[jj] += __shfl_down(s1[jj], off, 16);
          s2[jj] += __shfl_down(s2[jj], off, 16);
        }
      if (tr == 0)
        #pragma unroll
        for (int jj = 0; jj < 4; jj++) {
          pout[h*64 + 4*tc+jj]       = s1[jj];
          pout[128 + h*64 + 4*tc+jj] = s2[jj];
        }
      #pragma unroll
      for (int off = 4; off > 0; off >>= 1)
        #pragma unroll
        for (int jj = 0; jj < 4; jj++) {
          pmx[jj] = fmaxf(pmx[jj], __shfl_down(pmx[jj], off, 8));
          pmn[jj] = fminf(pmn[jj], __shfl_down(pmn[jj], off, 8));
        }
      if ((tr & 7) == 0) {
        int bs = (pb >> 5) + (tr >> 3);
        size_t ob = (size_t)bs*128 + h*64 + 4*tc;
        #pragma unroll
        for (int jj = 0; jj < 4; jj++) {
          pmax[ob + jj] = pmx[jj];
          pmin[ob + jj] = pmn[jj];
        }
      }
      __syncthreads();
    }
  }
}

// ---------------- fused_mid: load y1 -> bn1+relu -> gemm2 -> stats2, store y2 ----
__global__ __launch_bounds__(256) void fused_mid(
    const float* __restrict__ y1, const float* __restrict__ b1,
    const float* __restrict__ w2, const float* __restrict__ b2,
    const double* __restrict__ aff1,
    double* __restrict__ partial, float* __restrict__ y2) {
  __shared__ float wbuf[64*64];
  __shared__ float xsm[64*68];
  __shared__ float bsm[64];      // b1
  __shared__ float bsm2[64];     // b2
  __shared__ float sc1m[64], sh1m[64];
  const int t = threadIdx.x;
  const int pb = blockIdx.x * 64;
  const int tr = t & 15, tc = t >> 4;
  double* pout = partial + (size_t)blockIdx.x * 256;

  for (int ii = t; ii < 4096; ii += 256) {
    int oc = ii & 63, cc = ii >> 6;
    wbuf[cc*64 + oc] = w2[oc*64 + cc];
  }
  if (t < 64) {
    bsm[t] = b1[t]; bsm2[t] = b2[t];
    sc1m[t] = (float)aff1[t]; sh1m[t] = (float)aff1[128+t];
  }
  __syncthreads();
  {
    const int pxl = t >> 2, q = t & 3;
    const float* yrow = y1 + ((size_t)(pb + pxl))*64;
    #pragma unroll
    for (int u = 0; u < 4; u++) {
      int c0 = 4*q + 16*u;        // 4q mapping: 2-way LDS write aliasing (free)
      float4 v = *(const float4*)(yrow + c0);
      xsm[(c0+0)*68 + pxl] = fmaxf((v.x + bsm[c0+0])*sc1m[c0+0] + sh1m[c0+0], 0.f);
      xsm[(c0+1)*68 + pxl] = fmaxf((v.y + bsm[c0+1])*sc1m[c0+1] + sh1m[c0+1], 0.f);
      xsm[(c0+2)*68 + pxl] = fmaxf((v.z + bsm[c0+2])*sc1m[c0+2] + sh1m[c0+2], 0.f);
      xsm[(c0+3)*68 + pxl] = fmaxf((v.w + bsm[c0+3])*sc1m[c0+3] + sh1m[c0+3], 0.f);
    }
  }
  __syncthreads();

  float acc2[4][4] = {};
  for (int cc = 0; cc < 64; cc++) {
    float4 xv = *(const float4*)&xsm[cc*68 + 4*tr];
    float4 wv = *(const float4*)&wbuf[cc*64 + 4*tc];
    float xa[4] = {xv.x, xv.y, xv.z, xv.w};
    float wa[4] = {wv.x, wv.y, wv.z, wv.w};
    #pragma unroll
    for (int i = 0; i < 4; i++)
      #pragma unroll
      for (int jj = 0; jj < 4; jj++) acc2[i][jj] += xa[i]*wa[jj];
  }
  #pragma unroll
  for (int i = 0; i < 4; i++) {
    float4 o = make_float4(acc2[i][0], acc2[i][1], acc2[i][2], acc2[i][3]);
    *(float4*)(y2 + ((size_t)(pb + 4*tr + i))*64 + 4*tc) = o;
  }
  double s1[4] = {0,0,0,0}, s2[4] = {0,0,0,0};
  #pragma unroll
  for (int jj = 0; jj < 4; jj++) {
    float bb = bsm2[4*tc+jj];
    #pragma unroll
    for (int i = 0; i < 4; i++) {
      double yd = (double)(acc2[i][jj] + bb);
      s1[jj] += yd; s2[jj] += yd*yd;
    }
  }
  #pragma unroll
  for (int off = 8; off > 0; off >>= 1)
    #pragma unroll
    for (int jj = 0; jj < 4; jj++) {
      s1[jj] += __shfl_down(s1[jj], off, 16);
      s2[jj] += __shfl_down(s2[jj], off, 16);
    }
  if (tr == 0)
    #pragma unroll
    for (int jj = 0; jj < 4; jj++) {
      pout[4*tc+jj]       = s1[jj];
      pout[128 + 4*tc+jj] = s2[jj];
    }
}

// ---------------- fused_last: load y2 -> bn2+relu -> gemm3 -> stats3 + minmax ----
__global__ __launch_bounds__(256) void fused_last(
    const float* __restrict__ y2, const float* __restrict__ b2,
    const float* __restrict__ w3, const float* __restrict__ b3,
    const double* __restrict__ aff2,
    double* __restrict__ partial, float* __restrict__ pmax, float* __restrict__ pmin) {
  __shared__ float wbuf[64*64];
  __shared__ float xsm[64*68];
  __shared__ float bsm[64];      // b3 half
  __shared__ float bsm2[64];     // b2
  __shared__ float sc2m[64], sh2m[64];
  const int t = threadIdx.x;
  const int pb = blockIdx.x * 64;
  const int tr = t & 15, tc = t >> 4;
  double* pout = partial + (size_t)blockIdx.x * 256;

  if (t < 64) {
    bsm2[t] = b2[t];
    sc2m[t] = (float)aff2[t]; sh2m[t] = (float)aff2[128+t];
  }
  __syncthreads();
  {
    const int pxl = t >> 2, q = t & 3;
    const float* yrow = y2 + ((size_t)(pb + pxl))*64;
    #pragma unroll
    for (int u = 0; u < 4; u++) {
      int c0 = 4*q + 16*u;
      float4 v = *(const float4*)(yrow + c0);
      xsm[(c0+0)*68 + pxl] = fmaxf((v.x + bsm2[c0+0])*sc2m[c0+0] + sh2m[c0+0], 0.f);
      xsm[(c0+1)*68 + pxl] = fmaxf((v.y + bsm2[c0+1])*sc2m[c0+1] + sh2m[c0+1], 0.f);
      xsm[(c0+2)*68 + pxl] = fmaxf((v.z + bsm2[c0+2])*sc2m[c0+2] + sh2m[c0+2], 0.f);
      xsm[(c0+3)*68 + pxl] = fmaxf((v.w + bsm2[c0+3])*sc2m[c0+3] + sh2m[c0+3], 0.f);
    }
  }
  for (int h = 0; h < 2; h++) {
    for (int ii = t; ii < 4096; ii += 256) {
      int oc = ii & 63, cc = ii >> 6;
      wbuf[cc*64 + oc] = w3[(h*64 + oc)*64 + cc];
    }
    if (t < 64) bsm[t] = b3[h*64 + t];
    __syncthreads();
    float acc3[4][4] = {};
    for (int cc = 0; cc < 64; cc++) {
      float4 xv = *(const float4*)&xsm[cc*68 + 4*tr];
      float4 wv = *(const float4*)&wbuf[cc*64 + 4*tc];
      float xa[4] = {xv.x, xv.y, xv.z, xv.w};
      float wa[4] = {wv.x, wv.y, wv.z, wv.w};
      #pragma unroll
      for (int i = 0; i < 4; i++)
        #pragma unroll
        for (int jj = 0; jj < 4; jj++) acc3[i][jj] += xa[i]*wa[jj];
    }
    double s1[4] = {0,0,0,0}, s2[4] = {0,0,0,0};
    float pmx[4], pmn[4];
    #pragma unroll
    for (int jj = 0; jj < 4; jj++) { pmx[jj] = -3.4e38f; pmn[jj] = 3.4e38f; }
    #pragma unroll
    for (int jj = 0; jj < 4; jj++) {
      float bb = bsm[4*tc+jj];
      #pragma unroll
      for (int i = 0; i < 4; i++) {
        float y = acc3[i][jj] + bb;
        double yd = (double)y;
        s1[jj] += yd; s2[jj] += yd*yd;
        pmx[jj] = fmaxf(pmx[jj], y); pmn[jj] = fminf(pmn[jj], y);
      }
    }
    #pragma unroll
    for (int off = 8; off > 0; off >>= 1)
      #pragma unroll
      for (int jj = 0; jj < 4; jj++) {
        s1[jj] += __shfl_down(s1[jj], off, 16);
        s2[jj] += __shfl_down(s2[jj], off, 16);
      }
    if (tr == 0)
      #pragma unroll
      for (int jj = 0; jj < 4; jj++) {
        pout[h*64 + 4*tc+jj]       = s1[jj];
        pout[128 + h*64 + 4*tc+jj] = s2[jj];
      }
    #pragma unroll
    for (int off = 4; off > 0; off >>= 1)
      #pragma unroll
      for (int jj = 0; jj < 4; jj++) {
        pmx[jj] = fmaxf(pmx[jj], __shfl_down(pmx[jj], off, 8));
        pmn[jj] = fminf(pmn[jj], __shfl_down(pmn[jj], off, 8));
      }
    if ((tr & 7) == 0) {
      int bs = (pb >> 5) + (tr >> 3);
      size_t ob = (size_t)bs*128 + h*64 + 4*tc;
      #pragma unroll
      for (int jj = 0; jj < 4; jj++) {
        pmax[ob + jj] = pmx[jj];
        pmin[ob + jj] = pmn[jj];
      }
    }
    __syncthreads();
  }
}

// ---------------- reduce stage A: coalesced 8192->128 row reduction --------------
__global__ __launch_bounds__(256) void reduce_stageA(
    const double* __restrict__ partial, double* __restrict__ partial2) {
  const int t = threadIdx.x;
  const int bid = blockIdx.x;     // rows [bid*64, bid*64+64)
  const double* p = partial + (size_t)bid * 64 * 256 + t;
  double a0 = 0.0, a1 = 0.0, a2 = 0.0, a3 = 0.0;
  #pragma unroll 4
  for (int i = 0; i < 64; i += 4) {
    a0 += p[(size_t)(i+0)*256];
    a1 += p[(size_t)(i+1)*256];
    a2 += p[(size_t)(i+2)*256];
    a3 += p[(size_t)(i+3)*256];
  }
  partial2[(size_t)bid*256 + t] = (a0 + a1) + (a2 + a3);
}

// ---------------- reduce stage B: finalize over 128 rows + compute affine --------
__global__ __launch_bounds__(256) void reduce_finalize_kernel(
    const double* __restrict__ partial2,
    const float* __restrict__ g, const float* __restrict__ beta,
    double* __restrict__ aff) {
  __shared__ double sa1[4], sa2[4];
  const int c = blockIdx.x;
  const int t = threadIdx.x;
  double a1 = 0.0, a2 = 0.0;
  for (int blk = t; blk < 128; blk += 256) {
    a1 += partial2[(size_t)blk*256 + c];
    a2 += partial2[(size_t)blk*256 + 128 + c];
  }
  #pragma unroll
  for (int off = 32; off > 0; off >>= 1) {
    a1 += __shfl_down(a1, off);
    a2 += __shfl_down(a2, off);
  }
  const int lane = t & 63, wid = t >> 6;
  if (lane == 0) { sa1[wid] = a1; sa2[wid] = a2; }
  __syncthreads();
  if (t == 0) {
    double s1 = sa1[0] + sa1[1] + sa1[2] + sa1[3];
    double s2 = sa2[0] + sa2[1] + sa2[2] + sa2[3];
    const double invN = 1.0 / (double)NPIX;
    double mean = s1 * invN;
    double var  = s2 * invN - mean*mean;
    var = var > 0.0 ? var : 0.0;
    double r  = 1.0 / sqrt(var + BN_EPS);
    double sc = (double)g[c] * r;
    aff[c]       = sc;
    aff[128 + c] = (double)beta[c] - mean*sc;
  }
}

// ---------------- epilogue: bn3+relu on pooled extremum (monotone trick) ---------
__global__ __launch_bounds__(256) void out_kernel(
    const float* __restrict__ pmax, const float* __restrict__ pmin,
    const double* __restrict__ aff3, float* __restrict__ out_np) {
  int i = blockIdx.x * 256 + threadIdx.x;   // [0, 2097152)
  int oc = i & 127;
  double sc = aff3[oc], sh = aff3[128+oc];
  double v = (sc >= 0.0) ? (double)pmax[i] : (double)pmin[i];
  double y = v*sc + sh;
  out_np[i] = (float)(y > 0.0 ? y : 0.0);
}

extern "C" void kernel_launch(void* const* d_in, const int* in_sizes, int n_in,
                              void* d_out, int out_size, void* d_ws, size_t ws_size,
                              hipStream_t stream) {
  const float* xyz    = (const float*)d_in[0];
  const float* points = (const float*)d_in[1];
  const float* w1  = (const float*)d_in[2];
  const float* b1  = (const float*)d_in[3];
  const float* g1  = (const float*)d_in[4];
  const float* be1 = (const float*)d_in[5];
  const float* w2  = (const float*)d_in[6];
  const float* b2  = (const float*)d_in[7];
  const float* g2  = (const float*)d_in[8];
  const float* be2 = (const float*)d_in[9];
  const float* w3  = (const float*)d_in[10];
  const float* b3  = (const float*)d_in[11];
  const float* g3  = (const float*)d_in[12];
  const float* be3 = (const float*)d_in[13];

  char* ws = (char*)d_ws;
  double* aff     = (double*)(ws + 8192);      // 768 f64
  int*    cents   = (int*)  (ws + 16384);      // 16384 i32
  int*    idx     = (int*)  (ws + 81920);      // 524288 i32
  float*  pmax    = (float*)(ws + 2179072);    // 2097152 f32
  float*  pmin    = (float*)(ws + 10567680);   // 2097152 f32
  double* partial = (double*)(ws + 18956288);  // 8192*256 f64 = 16 MB, ends 35733504
  const size_t OFF_Y = 35733504;               // activation cache (gated on ws_size)
  const size_t SZ_Y  = (size_t)NPIX * 64 * 4;  // 134217728
  float* ycache1 = (float*)(ws + OFF_Y);
  float* ycache2 = (float*)(ws + OFF_Y + SZ_Y);
  const bool full_path = ws_size >= OFF_Y + 2*SZ_Y;   // >= ~304 MB
  const bool mid_path  = ws_size >= OFF_Y + SZ_Y;     // >= ~170 MB
  // stage-A scratch (128*256 f64 = 256 KB), borrowed from provably-dead regions:
  //  - p2a = pmax region (pmax written only AFTER reduces 1 & 2 in every path)
  //  - p2b = idx region (idx consumed BEFORE reduce 3 in every path)
  double* p2a = (double*)pmax;
  double* p2b = (double*)idx;
  float* out_xyz = (float*)d_out;                          // f32 new_xyz
  float* out_np  = (float*)d_out + (size_t)NB*NPOINT*3;    // f32 new_points

  fps_kernel        <<<16,   256, 0, stream>>>(xyz, cents, out_xyz);
  ballquery_kernel  <<<4096, 256, 0, stream>>>(xyz, cents, idx);
  if (full_path) {
    fused_pass<1,true>  <<<NBLK, 256, 0, stream>>>(xyz, points, cents, idx,
                                                   w1,b1,w2,b2,w3,b3,
                                                   aff, aff+256, partial, pmax, pmin,
                                                   ycache1);
    reduce_stageA     <<<128, 256, 0, stream>>>(partial, p2a);
    reduce_finalize_kernel<<<64, 256, 0, stream>>>(p2a, g1, be1, aff);
    fused_mid         <<<NBLK, 256, 0, stream>>>(ycache1, b1, w2, b2, aff, partial,
                                                 ycache2);
    reduce_stageA     <<<128, 256, 0, stream>>>(partial, p2a);
    reduce_finalize_kernel<<<64, 256, 0, stream>>>(p2a, g2, be2, aff+256);
    fused_last        <<<NBLK, 256, 0, stream>>>(ycache2, b2, w3, b3, aff+256,
                                                 partial, pmax, pmin);
    reduce_stageA     <<<128, 256, 0, stream>>>(partial, p2b);
    reduce_finalize_kernel<<<128, 256, 0, stream>>>(p2b, g3, be3, aff+512);
  } else if (mid_path) {
    fused_pass<1,false> <<<NBLK, 256, 0, stream>>>(xyz, points, cents, idx,
                                                   w1,b1,w2,b2,w3,b3,
                                                   aff, aff+256, partial, pmax, pmin,
                                                   nullptr);
    reduce_stageA     <<<128, 256, 0, stream>>>(partial, p2a);
    reduce_finalize_kernel<<<64, 256, 0, stream>>>(p2a, g1, be1, aff);
    fused_pass<2,true>  <<<NBLK, 256, 0, stream>>>(xyz, points, cents, idx,
                                                   w1,b1,w2,b2,w3,b3,
                                                   aff, aff+256, partial, pmax, pmin,
                                                   ycache1);
    reduce_stageA     <<<128, 256, 0, stream>>>(partial, p2a);
    reduce_finalize_kernel<<<64, 256, 0, stream>>>(p2a, g2, be2, aff+256);
    fused_last        <<<NBLK, 256, 0, stream>>>(ycache1, b2, w3, b3, aff+256,
                                                 partial, pmax, pmin);
    reduce_stageA     <<<128, 256, 0, stream>>>(partial, p2b);
    reduce_finalize_kernel<<<128, 256, 0, stream>>>(p2b, g3, be3, aff+512);
  } else {
    fused_pass<1,false> <<<NBLK, 256, 0, stream>>>(xyz, points, cents, idx,
                                                   w1,b1,w2,b2,w3,b3,
                                                   aff, aff+256, partial, pmax, pmin,
                                                   nullptr);
    reduce_stageA     <<<128, 256, 0, stream>>>(partial, p2a);
    reduce_finalize_kernel<<<64, 256, 0, stream>>>(p2a, g1, be1, aff);
    fused_pass<2,false> <<<NBLK, 256, 0, stream>>>(xyz, points, cents, idx,
                                                   w1,b1,w2,b2,w3,b3,
                                                   aff, aff+256, partial, pmax, pmin,
                                                   nullptr);
    reduce_stageA     <<<128, 256, 0, stream>>>(partial, p2a);
    reduce_finalize_kernel<<<64, 256, 0, stream>>>(p2a, g2, be2, aff+256);
    fused_pass<3,false> <<<NBLK, 256, 0, stream>>>(xyz, points, cents, idx,
                                                   w1,b1,w2,b2,w3,b3,
                                                   aff, aff+256, partial, pmax, pmin,
                                                   nullptr);
    reduce_stageA     <<<128, 256, 0, stream>>>(partial, p2b);
    reduce_finalize_kernel<<<128, 256, 0, stream>>>(p2b, g3, be3, aff+512);
  }
  out_kernel        <<<NBLK, 256, 0, stream>>>(pmax, pmin, aff+512, out_np);
}